// Round 8
// baseline (717.426 us; speedup 1.0000x reference)
//
#include <hip/hip_runtime.h>
#include <cstdint>
#include <cstddef>

#define B_    16
#define P_    10
#define S_    128
#define D_    512
#define H_    8
#define DH_   64
#define DFF_  2048
#define VOC_  32000
#define NROW  160   // B*P
#define SIGMA 0.05f
#define LN_EPS 1e-6f

// ---------------- Threefry2x32 (bit-exact vs JAX) ----------------
struct U2 { uint32_t x, y; };

__host__ __device__ __forceinline__ U2 tf2x32(uint32_t k0, uint32_t k1,
                                              uint32_t x0, uint32_t x1) {
  uint32_t ks[3] = {k0, k1, k0 ^ k1 ^ 0x1BD11BDAu};
  x0 += ks[0]; x1 += ks[1];
  const int R0[4] = {13, 15, 26, 6};
  const int R1[4] = {17, 29, 16, 24};
#pragma unroll
  for (int i = 0; i < 5; ++i) {
    const int* r = (i & 1) ? R1 : R0;
#pragma unroll
    for (int j = 0; j < 4; ++j) {
      x0 += x1;
      x1 = (x1 << r[j]) | (x1 >> (32 - r[j]));
      x1 ^= x0;
    }
    x0 += ks[(i + 1) % 3];
    x1 += ks[(i + 2) % 3] + (uint32_t)(i + 1);
  }
  return {x0, x1};
}

__device__ __forceinline__ uint32_t jax_bits32(uint32_t k0, uint32_t k1, uint32_t j) {
  U2 o = tf2x32(k0, k1, 0u, j);
  return o.x ^ o.y;
}

__device__ __forceinline__ float erfinv32(float x) {
  float w = -log1pf(-x * x);
  float p;
  if (w < 5.0f) {
    w = w - 2.5f;
    p = 2.81022636e-08f;
    p = fmaf(p, w, 3.43273939e-07f);
    p = fmaf(p, w, -3.5233877e-06f);
    p = fmaf(p, w, -4.39150654e-06f);
    p = fmaf(p, w, 0.00021858087f);
    p = fmaf(p, w, -0.00125372503f);
    p = fmaf(p, w, -0.00417768164f);
    p = fmaf(p, w, 0.246640727f);
    p = fmaf(p, w, 1.50140941f);
  } else {
    w = sqrtf(w) - 3.0f;
    p = -0.000200214257f;
    p = fmaf(p, w, 0.000100950558f);
    p = fmaf(p, w, 0.00134934322f);
    p = fmaf(p, w, -0.00367342844f);
    p = fmaf(p, w, 0.00573950773f);
    p = fmaf(p, w, -0.0076224613f);
    p = fmaf(p, w, 0.00943887047f);
    p = fmaf(p, w, 1.00167406f);
    p = fmaf(p, w, 2.83297682f);
  }
  return p * x;
}

__device__ __forceinline__ float jax_normal(uint32_t k0, uint32_t k1, uint32_t j) {
  uint32_t b = jax_bits32(k0, k1, j);
  float u01 = __uint_as_float((b >> 9) | 0x3F800000u) - 1.0f;
  const float lo = -0.99999994f;
  float u = fmaxf(lo, fmaf(u01, 2.0f, lo));
  return 1.41421356f * erfinv32(u);
}

__device__ __forceinline__ float jax_gumbel(uint32_t k0, uint32_t k1, uint32_t j) {
  uint32_t b = jax_bits32(k0, k1, j);
  float u01 = __uint_as_float((b >> 9) | 0x3F800000u) - 1.0f;
  const float tiny = 1.17549435e-38f;
  float u = fmaxf(tiny, u01 + tiny);
  return -logf(-logf(u));
}

// ---------------- Kernels ----------------

// Gather K,V by particle index I along axis 1
__global__ __launch_bounds__(256) void k_gather(const float* __restrict__ K,
                                                const float* __restrict__ V,
                                                const int* __restrict__ I,
                                                float* __restrict__ oK,
                                                float* __restrict__ oV) {
  size_t idx = (size_t)blockIdx.x * 256 + threadIdx.x;        // float4 index
  const size_t total = (size_t)NROW * S_ * (D_ / 4);
  if (idx >= total) return;
  int d4 = (int)(idx % (D_ / 4));
  size_t row = idx / (D_ / 4);                                 // bp*S + s
  int s = (int)(row % S_);
  int bp = (int)(row / S_);
  int b = bp / P_;
  int iv = I[row];
  size_t src = ((size_t)(b * P_ + iv) * S_ + s) * (D_ / 4) + d4;
  ((float4*)oK)[idx] = ((const float4*)K)[src];
  ((float4*)oV)[idx] = ((const float4*)V)[src];
}

// qkv partial: grid (4 col-chunks, 40 row-tiles, 8 k-chunks of 64), 128 thr.
__global__ __launch_bounds__(128) void k_qkvp(const float* __restrict__ r,
    const float* __restrict__ Wq, const float* __restrict__ bq,
    const float* __restrict__ Wk, const float* __restrict__ bk,
    const float* __restrict__ Wv, const float* __restrict__ bv,
    float* __restrict__ pq, float* __restrict__ pk, float* __restrict__ pv) {
  int c = blockIdx.x * 128 + threadIdx.x;
  int r0 = blockIdx.y * 4;
  int kc = blockIdx.z;
  int d0 = kc * 64;
  float aq[4], ak[4], av[4];
  float bbq = (kc == 0) ? bq[c] : 0.f;
  float bbk = (kc == 0) ? bk[c] : 0.f;
  float bbv = (kc == 0) ? bv[c] : 0.f;
#pragma unroll
  for (int rr = 0; rr < 4; ++rr) { aq[rr] = bbq; ak[rr] = bbk; av[rr] = bbv; }
  for (int d = d0; d < d0 + 64; d += 4) {
    float wq0 = Wq[(size_t)d * D_ + c],      wq1 = Wq[(size_t)(d+1) * D_ + c];
    float wq2 = Wq[(size_t)(d+2) * D_ + c],  wq3 = Wq[(size_t)(d+3) * D_ + c];
    float wk0 = Wk[(size_t)d * D_ + c],      wk1 = Wk[(size_t)(d+1) * D_ + c];
    float wk2 = Wk[(size_t)(d+2) * D_ + c],  wk3 = Wk[(size_t)(d+3) * D_ + c];
    float wv0 = Wv[(size_t)d * D_ + c],      wv1 = Wv[(size_t)(d+1) * D_ + c];
    float wv2 = Wv[(size_t)(d+2) * D_ + c],  wv3 = Wv[(size_t)(d+3) * D_ + c];
#pragma unroll
    for (int rr = 0; rr < 4; ++rr) {
      float4 a = *(const float4*)&r[(size_t)(r0 + rr) * D_ + d];
      aq[rr] = fmaf(a.w, wq3, fmaf(a.z, wq2, fmaf(a.y, wq1, fmaf(a.x, wq0, aq[rr]))));
      ak[rr] = fmaf(a.w, wk3, fmaf(a.z, wk2, fmaf(a.y, wk1, fmaf(a.x, wk0, ak[rr]))));
      av[rr] = fmaf(a.w, wv3, fmaf(a.z, wv2, fmaf(a.y, wv1, fmaf(a.x, wv0, av[rr]))));
    }
  }
#pragma unroll
  for (int rr = 0; rr < 4; ++rr) {
    size_t o = ((size_t)kc * NROW + r0 + rr) * D_ + c;
    pq[o] = aq[rr]; pk[o] = ak[rr]; pv[o] = av[rr];
  }
}

// qkv reduce: sum 8 partials (ascending), add noise, scatter K/V at ts.
__global__ __launch_bounds__(256) void k_qkvr(const float* __restrict__ pq,
    const float* __restrict__ pk, const float* __restrict__ pv,
    const int* __restrict__ tptr, float* __restrict__ wsq,
    float* __restrict__ oK, float* __restrict__ oV,
    uint32_t k1a, uint32_t k1b, uint32_t k2a, uint32_t k2b,
    uint32_t k3a, uint32_t k3b) {
  int idx = blockIdx.x * 256 + threadIdx.x;
  if (idx >= NROW * D_) return;
  float q = pq[idx], k = pk[idx], v = pv[idx];
#pragma unroll
  for (int kc = 1; kc < 8; ++kc) {
    size_t o = (size_t)kc * (NROW * D_) + idx;
    q += pq[o]; k += pk[o]; v += pv[o];
  }
  int bp = idx / D_, c = idx % D_;
  int ts = min(max(*tptr, 0), S_ - 1);
  uint32_t j = (uint32_t)idx;
  wsq[idx] = q + SIGMA * jax_normal(k1a, k1b, j);
  oK[((size_t)bp * S_ + ts) * D_ + c] = k + SIGMA * jax_normal(k2a, k2b, j);
  oV[((size_t)bp * S_ + ts) * D_ + c] = v + SIGMA * jax_normal(k3a, k3b, j);
}

// attention: one block per (bp, h); 128 threads (one per s).
// PV uses all 128 lanes: two s-halves, LDS combine.
__global__ __launch_bounds__(128) void k_attn(const float* __restrict__ wsq,
    const float* __restrict__ oK, const float* __restrict__ oV,
    float* __restrict__ wsctx, float* __restrict__ wsattn) {
  __shared__ float s_q[DH_];
  __shared__ float s_attn[S_];
  __shared__ float red[S_];
  int bp = blockIdx.x >> 3, h = blockIdx.x & 7, tid = threadIdx.x;
  if (tid < DH_) s_q[tid] = wsq[bp * D_ + h * DH_ + tid];
  __syncthreads();
  const float4* krow = (const float4*)(oK + ((size_t)bp * S_ + tid) * D_ + h * DH_);
  const float4* q4 = (const float4*)s_q;
  float sc = 0.f;
#pragma unroll
  for (int d = 0; d < DH_ / 4; ++d) {
    float4 kv = krow[d], qv = q4[d];
    sc += qv.x * kv.x + qv.y * kv.y + qv.z * kv.z + qv.w * kv.w;
  }
  sc *= 0.125f;  // 1/sqrt(64)
  red[tid] = sc; __syncthreads();
  for (int s = 64; s > 0; s >>= 1) {
    if (tid < s) red[tid] = fmaxf(red[tid], red[tid + s]);
    __syncthreads();
  }
  float m = red[0]; __syncthreads();
  float e = expf(sc - m);
  red[tid] = e; __syncthreads();
  for (int s = 64; s > 0; s >>= 1) {
    if (tid < s) red[tid] += red[tid + s];
    __syncthreads();
  }
  float a = e / red[0];
  s_attn[tid] = a;
  wsattn[(size_t)blockIdx.x * S_ + tid] = a;
  __syncthreads();
  {
    int dd = tid & 63, sh = tid >> 6;   // sh in {0,1}: s-half
    const float* vb = oV + ((size_t)bp * S_ + sh * 64) * D_ + h * DH_ + dd;
    float acc = 0.f;
#pragma unroll 4
    for (int s = 0; s < 64; ++s) acc = fmaf(s_attn[sh * 64 + s], vb[(size_t)s * D_], acc);
    red[tid] = acc; __syncthreads();
    if (tid < DH_) wsctx[bp * D_ + h * DH_ + tid] = red[tid] + red[tid + 64];
  }
}

// attn_weights = mean over heads
__global__ __launch_bounds__(256) void k_aw(const float* __restrict__ wsattn,
                                            float* __restrict__ oaw) {
  int idx = blockIdx.x * 256 + threadIdx.x;
  if (idx >= NROW * S_) return;
  int bp = idx / S_, s = idx % S_;
  float acc = 0.f;
#pragma unroll
  for (int h = 0; h < H_; ++h) acc += wsattn[(size_t)(bp * H_ + h) * S_ + s];
  oaw[idx] = acc * 0.125f;
}

// zmat partial: grid (4, 40, 8 k-chunks of 64), 128 thr.  kc==0 carries bias.
__global__ __launch_bounds__(128) void k_zmatp(const float* __restrict__ wsctx,
    const float* __restrict__ Wo, const float* __restrict__ bo,
    float* __restrict__ pz) {
  int c = blockIdx.x * 128 + threadIdx.x;
  int r0 = blockIdx.y * 4;
  int kc = blockIdx.z;
  int d0 = kc * 64;
  float acc[4];
  float bb = (kc == 0) ? bo[c] : 0.f;
#pragma unroll
  for (int rr = 0; rr < 4; ++rr) acc[rr] = bb;
  for (int d = d0; d < d0 + 64; d += 4) {
    float w0 = Wo[(size_t)d * D_ + c],     w1 = Wo[(size_t)(d+1) * D_ + c];
    float w2 = Wo[(size_t)(d+2) * D_ + c], w3 = Wo[(size_t)(d+3) * D_ + c];
#pragma unroll
    for (int rr = 0; rr < 4; ++rr) {
      float4 a = *(const float4*)&wsctx[(size_t)(r0 + rr) * D_ + d];
      acc[rr] = fmaf(a.w, w3, fmaf(a.z, w2, fmaf(a.y, w1, fmaf(a.x, w0, acc[rr]))));
    }
  }
#pragma unroll
  for (int rr = 0; rr < 4; ++rr)
    pz[((size_t)kc * NROW + r0 + rr) * D_ + c] = acc[rr];
}

// FUSED zmat-reduce + LN1: one block per row (160 blocks, 256 thr, 2 elem/thr).
__global__ __launch_bounds__(256) void k_zmatr_ln(const float* __restrict__ pz,
    const float* __restrict__ r, const float* __restrict__ g,
    const float* __restrict__ b, float* __restrict__ oeps,
    float* __restrict__ wsz, float* __restrict__ o,
    uint32_t k4a, uint32_t k4b) {
  __shared__ float red[256];
  int bp = blockIdx.x, tid = threadIdx.x;
  float x0, x1;
  {
    int idx = bp * D_ + tid;
    float s = pz[idx];
#pragma unroll
    for (int kc = 1; kc < 8; ++kc) s += pz[(size_t)kc * (NROW * D_) + idx];
    float eps = SIGMA * jax_normal(k4a, k4b, (uint32_t)idx);
    oeps[idx] = eps;
    float z = s + eps;
    wsz[idx] = z;
    x0 = z + r[idx];
  }
  {
    int idx = bp * D_ + tid + 256;
    float s = pz[idx];
#pragma unroll
    for (int kc = 1; kc < 8; ++kc) s += pz[(size_t)kc * (NROW * D_) + idx];
    float eps = SIGMA * jax_normal(k4a, k4b, (uint32_t)idx);
    oeps[idx] = eps;
    float z = s + eps;
    wsz[idx] = z;
    x1 = z + r[idx];
  }
  red[tid] = x0 + x1; __syncthreads();
  for (int s = 128; s > 0; s >>= 1) { if (tid < s) red[tid] += red[tid + s]; __syncthreads(); }
  float mu = red[0] / (float)D_; __syncthreads();
  float d0 = x0 - mu, d1 = x1 - mu;
  red[tid] = d0 * d0 + d1 * d1; __syncthreads();
  for (int s = 128; s > 0; s >>= 1) { if (tid < s) red[tid] += red[tid + s]; __syncthreads(); }
  float inv = 1.0f / sqrtf(red[0] / (float)D_ + LN_EPS);
  o[bp * D_ + tid] = g[tid] * d0 * inv + b[tid];
  o[bp * D_ + tid + 256] = g[tid + 256] * d1 * inv + b[tid + 256];
}

// ffn1 partial: grid (16, 20, 4 k-chunks of 128), 128 thr.  kc==0 carries b1.
__global__ __launch_bounds__(128) void k_ffn1p(const float* __restrict__ wsout1,
    const float* __restrict__ W1, const float* __restrict__ b1,
    float* __restrict__ pf) {
  int c = blockIdx.x * 128 + threadIdx.x;
  int r0 = blockIdx.y * 8;
  int kc = blockIdx.z;
  int d0 = kc * 128;
  float acc[8];
  float bb = (kc == 0) ? b1[c] : 0.f;
#pragma unroll
  for (int rr = 0; rr < 8; ++rr) acc[rr] = bb;
  for (int d = d0; d < d0 + 128; d += 4) {
    float w0 = W1[(size_t)d * DFF_ + c],     w1 = W1[(size_t)(d+1) * DFF_ + c];
    float w2 = W1[(size_t)(d+2) * DFF_ + c], w3 = W1[(size_t)(d+3) * DFF_ + c];
#pragma unroll
    for (int rr = 0; rr < 8; ++rr) {
      float4 a = *(const float4*)&wsout1[(size_t)(r0 + rr) * D_ + d];
      acc[rr] = fmaf(a.w, w3, fmaf(a.z, w2, fmaf(a.y, w1, fmaf(a.x, w0, acc[rr]))));
    }
  }
#pragma unroll
  for (int rr = 0; rr < 8; ++rr)
    pf[((size_t)kc * NROW + r0 + rr) * DFF_ + c] = acc[rr];
}

// ffn1 reduce + relu
__global__ __launch_bounds__(256) void k_ffn1r(const float* __restrict__ pf,
    float* __restrict__ wsffn) {
  int idx = blockIdx.x * 256 + threadIdx.x;
  if (idx >= NROW * DFF_) return;
  float s = pf[idx];
#pragma unroll
  for (int kc = 1; kc < 4; ++kc) s += pf[(size_t)kc * (NROW * DFF_) + idx];
  wsffn[idx] = fmaxf(s, 0.f);
}

// ffn2 partial: grid (4, 40, 16 k-chunks of 128), 128 thr.
__global__ __launch_bounds__(128) void k_ffn2p(const float* __restrict__ wsffn,
    const float* __restrict__ W2, float* __restrict__ p2) {
  int c = blockIdx.x * 128 + threadIdx.x;
  int r0 = blockIdx.y * 4;
  int kc = blockIdx.z;
  int d0 = kc * 128;
  float acc[4];
#pragma unroll
  for (int rr = 0; rr < 4; ++rr) acc[rr] = 0.f;
  for (int d = d0; d < d0 + 128; d += 4) {
    float w0 = W2[(size_t)d * D_ + c],     w1 = W2[(size_t)(d+1) * D_ + c];
    float w2 = W2[(size_t)(d+2) * D_ + c], w3 = W2[(size_t)(d+3) * D_ + c];
#pragma unroll
    for (int rr = 0; rr < 4; ++rr) {
      float4 a = *(const float4*)&wsffn[(size_t)(r0 + rr) * DFF_ + d];
      acc[rr] = fmaf(a.w, w3, fmaf(a.z, w2, fmaf(a.y, w1, fmaf(a.x, w0, acc[rr]))));
    }
  }
#pragma unroll
  for (int rr = 0; rr < 4; ++rr)
    p2[((size_t)kc * NROW + r0 + rr) * D_ + c] = acc[rr];
}

// FUSED ffn2-reduce + LN3: writes out3 directly.
__global__ __launch_bounds__(256) void k_ffn2r_ln(const float* __restrict__ p2,
    const float* __restrict__ b2, const float* __restrict__ wsout1,
    const float* __restrict__ g, const float* __restrict__ b,
    float* __restrict__ o) {
  __shared__ float red[256];
  int bp = blockIdx.x, tid = threadIdx.x;
  float x0, x1;
  {
    int idx = bp * D_ + tid;
    float s = p2[idx];
#pragma unroll
    for (int kc = 1; kc < 16; ++kc) s += p2[(size_t)kc * (NROW * D_) + idx];
    x0 = s + b2[tid] + wsout1[idx];
  }
  {
    int idx = bp * D_ + tid + 256;
    float s = p2[idx];
#pragma unroll
    for (int kc = 1; kc < 16; ++kc) s += p2[(size_t)kc * (NROW * D_) + idx];
    x1 = s + b2[tid + 256] + wsout1[idx];
  }
  red[tid] = x0 + x1; __syncthreads();
  for (int s = 128; s > 0; s >>= 1) { if (tid < s) red[tid] += red[tid + s]; __syncthreads(); }
  float mu = red[0] / (float)D_; __syncthreads();
  float d0 = x0 - mu, d1 = x1 - mu;
  red[tid] = d0 * d0 + d1 * d1; __syncthreads();
  for (int s = 128; s > 0; s >>= 1) { if (tid < s) red[tid] += red[tid + s]; __syncthreads(); }
  float inv = 1.0f / sqrtf(red[0] / (float)D_ + LN_EPS);
  o[bp * D_ + tid] = g[tid] * d0 * inv + b[tid];
  o[bp * D_ + tid + 256] = g[tid + 256] * d1 * inv + b[tid + 256];
}

// zero wspred for k_preds atomic accumulation
__global__ __launch_bounds__(256) void k_zero(float4* __restrict__ p) {
  int idx = blockIdx.x * 256 + threadIdx.x;
  if (idx < (NROW * VOC_) / 4) p[idx] = float4{0.f, 0.f, 0.f, 0.f};
}

// predictions = out3 @ Wout + bout  (160 x 512 x 32000)
// K-SPLIT x R2-SHAPE: duty model from R2-R6 says VALUBusy ~ waves/SIMD x
// per-wave duty; the 8-col/40-acc shape has duty 0.232 (R2: 36.2% @ 1.56 w/S)
// but only 2000 waves exist at that shape -> grid-starved.  Split D into 2
// halves across blockIdx.z -> 4000 waves; 128-thr blocks, LDS 21.8KB -> 7
// blocks/CU resident -> ~3.5 w/SIMD x 0.232 ~ 75% VALU target.
// Merge: wspred pre-zeroed (k_zero); both halves atomicAdd.  Exactly two
// commutative fp32 adds per element (bias folded into kc=0 chain) -> bit-
// deterministic, same k-split semantics as R2-R6 (absmax 0.0039).
// No cross-half barriers (R5 lesson), no held prefetch regs (R4/R6 lesson).
// Block: 80 rows x 64 cols x 256 d; thread: 5 rows x 8 cols (40 acc).
// Grid (500, 2, 2).  VGPR ~90 < 128 cap (launch_bounds(128,4)).
__global__ __launch_bounds__(128, 4) void k_preds(const float* __restrict__ A,
    const float* __restrict__ Wout, const float* __restrict__ bout,
    float* __restrict__ wspred) {
  __shared__ float sA[80][68];   // 21.76 KB
  int tid = threadIdx.x;
  int cb = blockIdx.x, rh = blockIdx.y, kc = blockIdx.z;
  int cg = tid & 7, rg = tid >> 3;    // 8 cg x 8 cols; 16 rg x 5 rows
  int c = cb * 64 + cg * 8;
  const float* Ab = A + (size_t)rh * 80 * D_;
  const float* Wp = Wout + c;
  const int dbase = kc * 256;
  float4 acc[5][2];
  if (kc == 0) {
    float4 b0 = *(const float4*)&bout[c];
    float4 b1 = *(const float4*)&bout[c + 4];
#pragma unroll
    for (int i = 0; i < 5; ++i) { acc[i][0] = b0; acc[i][1] = b1; }
  } else {
    float4 z = {0.f, 0.f, 0.f, 0.f};
#pragma unroll
    for (int i = 0; i < 5; ++i) { acc[i][0] = z; acc[i][1] = z; }
  }
  for (int t = 0; t < 4; ++t) {
    int d0 = dbase + t * 64;
    if (t) __syncthreads();          // previous chunk's reads done
    // stage A[0:80][d0:d0+64]: 1280 float4, 10 per thread, coalesced
#pragma unroll
    for (int k = 0; k < 10; ++k) {
      int idx = tid + k * 128;
      int row = idx >> 4, c4 = idx & 15;
      *(float4*)&sA[row][c4 * 4] =
          *(const float4*)&Ab[(size_t)row * D_ + d0 + c4 * 4];
    }
    __syncthreads();
#pragma unroll 2
    for (int dd = 0; dd < 64; dd += 4) {
      size_t wb = (size_t)(d0 + dd) * VOC_;
      float4 w00 = *(const float4*)&Wp[wb];
      float4 w01 = *(const float4*)&Wp[wb + 4];
      float4 w10 = *(const float4*)&Wp[wb + VOC_];
      float4 w11 = *(const float4*)&Wp[wb + VOC_ + 4];
      float4 w20 = *(const float4*)&Wp[wb + 2 * (size_t)VOC_];
      float4 w21 = *(const float4*)&Wp[wb + 2 * (size_t)VOC_ + 4];
      float4 w30 = *(const float4*)&Wp[wb + 3 * (size_t)VOC_];
      float4 w31 = *(const float4*)&Wp[wb + 3 * (size_t)VOC_ + 4];
#define FMA8(av, wA, wB)                                   \
      acc[i][0].x = fmaf(av, wA.x, acc[i][0].x);           \
      acc[i][0].y = fmaf(av, wA.y, acc[i][0].y);           \
      acc[i][0].z = fmaf(av, wA.z, acc[i][0].z);           \
      acc[i][0].w = fmaf(av, wA.w, acc[i][0].w);           \
      acc[i][1].x = fmaf(av, wB.x, acc[i][1].x);           \
      acc[i][1].y = fmaf(av, wB.y, acc[i][1].y);           \
      acc[i][1].z = fmaf(av, wB.z, acc[i][1].z);           \
      acc[i][1].w = fmaf(av, wB.w, acc[i][1].w);
#pragma unroll
      for (int i = 0; i < 5; ++i) {
        float4 a = *(const float4*)&sA[rg * 5 + i][dd];
        FMA8(a.x, w00, w01)
        FMA8(a.y, w10, w11)
        FMA8(a.z, w20, w21)
        FMA8(a.w, w30, w31)
      }
#undef FMA8
    }
  }
#pragma unroll
  for (int i = 0; i < 5; ++i) {
    size_t o = (size_t)(rh * 80 + rg * 5 + i) * VOC_ + c;
    atomicAdd(&wspred[o + 0], acc[i][0].x);
    atomicAdd(&wspred[o + 1], acc[i][0].y);
    atomicAdd(&wspred[o + 2], acc[i][0].z);
    atomicAdd(&wspred[o + 3], acc[i][0].w);
    atomicAdd(&wspred[o + 4], acc[i][1].x);
    atomicAdd(&wspred[o + 5], acc[i][1].y);
    atomicAdd(&wspred[o + 6], acc[i][1].z);
    atomicAdd(&wspred[o + 7], acc[i][1].w);
  }
}

// per-row softmax stats over VOC; w[b,p] = probs at x[b]
__global__ __launch_bounds__(256) void k_stats(const float* __restrict__ wspred,
    const int* __restrict__ x, float* __restrict__ ow) {
  __shared__ float red[256];
  int bp = blockIdx.x, tid = threadIdx.x;
  const float* row = wspred + (size_t)bp * VOC_;
  const float4* row4 = (const float4*)row;
  float m = -INFINITY;
  for (int i = tid; i < VOC_ / 4; i += 256) {
    float4 v = row4[i];
    m = fmaxf(m, fmaxf(fmaxf(v.x, v.y), fmaxf(v.z, v.w)));
  }
  red[tid] = m; __syncthreads();
  for (int s = 128; s > 0; s >>= 1) { if (tid < s) red[tid] = fmaxf(red[tid], red[tid + s]); __syncthreads(); }
  m = red[0]; __syncthreads();
  float sum = 0.f;
  for (int i = tid; i < VOC_ / 4; i += 256) {
    float4 v = row4[i];
    sum += expf(v.x - m) + expf(v.y - m) + expf(v.z - m) + expf(v.w - m);
  }
  red[tid] = sum; __syncthreads();
  for (int s = 128; s > 0; s >>= 1) { if (tid < s) red[tid] += red[tid + s]; __syncthreads(); }
  if (tid == 0) {
    int b = bp / P_;
    ow[bp] = expf(row[x[b]] - m) / red[0];
  }
}

// i_t via gumbel-argmax; argmax_w per batch
__global__ __launch_bounds__(256) void k_it(const float* __restrict__ ow,
    int* __restrict__ wsit, int* __restrict__ wsamw,
    uint32_t k5a, uint32_t k5b) {
  int tid = threadIdx.x;
  if (tid < NROW) {
    int b = tid / P_;
    float best = -INFINITY; int bi = 0;
#pragma unroll
    for (int i = 0; i < P_; ++i) {
      float g = jax_gumbel(k5a, k5b, (uint32_t)(tid * P_ + i));
      float v = g + ow[b * P_ + i];
      if (v > best) { best = v; bi = i; }
    }
    wsit[tid] = bi;
  }
  if (tid < B_) {
    float best = -INFINITY; int bi = 0;
#pragma unroll
    for (int p = 0; p < P_; ++p) {
      float v = ow[tid * P_ + p];
      if (v > best) { best = v; bi = p; }
    }
    wsamw[tid] = bi;
  }
}

// MERGED tail: blocks [0,2000) = avgmax; blocks [2000,2320) = zsel+I_new.
__global__ __launch_bounds__(256) void k_tail(const float* __restrict__ wspred,
    const float* __restrict__ ow, const int* __restrict__ wsamw,
    const float* __restrict__ wsz, const int* __restrict__ wsit,
    const int* __restrict__ I, const int* __restrict__ tptr,
    float* __restrict__ oavg, float* __restrict__ omax,
    float* __restrict__ oz, float* __restrict__ oI) {
  int bid = blockIdx.x, tid = threadIdx.x;
  if (bid < 2000) {
    int idx = bid * 256 + tid;
    if (idx >= B_ * VOC_) return;
    int b = idx / VOC_, c = idx % VOC_;
    float acc = 0.f;
#pragma unroll
    for (int p = 0; p < P_; ++p)
      acc = fmaf(wspred[(size_t)(b * P_ + p) * VOC_ + c], ow[b * P_ + p], acc);
    oavg[idx] = acc;
    omax[idx] = wspred[(size_t)(b * P_ + wsamw[b]) * VOC_ + c];
  } else {
    int idx = (bid - 2000) * 256 + tid;
    if (idx < NROW * D_) {
      int bp = idx / D_, d = idx % D_;
      int b = bp / P_;
      oz[idx] = wsz[(size_t)(b * P_ + wsit[bp]) * D_ + d];
    }
    if (idx < NROW * S_) {
      int bp = idx / S_, s = idx % S_;
      int ts = min(max(*tptr, 0), S_ - 1);
      oI[idx] = (s == ts) ? (float)wsit[bp] : (float)I[idx];
    }
  }
}

// ---------------- Host launch ----------------
static void derive_keys(uint32_t keys[5][2]) {
  for (int i = 0; i < 5; ++i) {
    U2 o = tf2x32(0u, 42u, 0u, (uint32_t)i);
    keys[i][0] = o.x; keys[i][1] = o.y;
  }
}

extern "C" void kernel_launch(void* const* d_in, const int* in_sizes, int n_in,
                              void* d_out, int out_size, void* d_ws, size_t ws_size,
                              hipStream_t stream) {
  const float* r   = (const float*)d_in[0];
  const int*   x   = (const int*)d_in[1];
  const float* K   = (const float*)d_in[2];
  const float* V   = (const float*)d_in[3];
  const int*   I   = (const int*)d_in[5];
  const int*   tp  = (const int*)d_in[6];
  const float* Wq  = (const float*)d_in[7];
  const float* bq  = (const float*)d_in[8];
  const float* Wk  = (const float*)d_in[9];
  const float* bk  = (const float*)d_in[10];
  const float* Wv  = (const float*)d_in[11];
  const float* bv  = (const float*)d_in[12];
  const float* Wo  = (const float*)d_in[13];
  const float* bo  = (const float*)d_in[14];
  const float* W1  = (const float*)d_in[15];
  const float* b1  = (const float*)d_in[16];
  const float* W2  = (const float*)d_in[17];
  const float* b2  = (const float*)d_in[18];
  const float* g1  = (const float*)d_in[19];
  const float* be1 = (const float*)d_in[20];
  const float* g3  = (const float*)d_in[21];
  const float* be3 = (const float*)d_in[22];
  const float* Wout = (const float*)d_in[23];
  const float* bout = (const float*)d_in[24];

  float* out = (float*)d_out;
  const size_t O_OUT3 = 0;
  const size_t O_Z    = 81920;
  const size_t O_AVG  = 163840;
  const size_t O_MAX  = 675840;
  const size_t O_EPS  = 1187840;
  const size_t O_AW   = 1269760;
  const size_t O_K    = 1290240;
  const size_t O_V    = 11776000;
  const size_t O_W    = 22261760;
  const size_t O_I    = 22261920;

  float* ws = (float*)d_ws;
  const size_t W_Q    = 0;
  const size_t W_CTX  = 81920;
  const size_t W_Z    = 163840;
  const size_t W_OUT1 = 245760;
  const size_t W_ATT  = 327680;   // 163840
  const size_t W_FFN  = 491520;   // 327680
  const size_t W_PRED = 819200;   // 5120000 -- also reused as K-split scratch
  const size_t W_IT   = 5939200;
  const size_t W_AMW  = 5939360;

  uint32_t kk[5][2];
  derive_keys(kk);

  float* oK = out + O_K;
  float* oV = out + O_V;
  float* sc = ws + W_PRED;        // K-split partial scratch (dead before k_preds)

  k_gather<<<10240, 256, 0, stream>>>(K, V, I, oK, oV);
  k_qkvp<<<dim3(4, 40, 8), 128, 0, stream>>>(r, Wq, bq, Wk, bk, Wv, bv,
                                             sc, sc + 655360, sc + 1310720);
  k_qkvr<<<320, 256, 0, stream>>>(sc, sc + 655360, sc + 1310720, tp,
                                  ws + W_Q, oK, oV,
                                  kk[0][0], kk[0][1], kk[1][0], kk[1][1],
                                  kk[2][0], kk[2][1]);
  k_attn<<<NROW * H_, 128, 0, stream>>>(ws + W_Q, oK, oV, ws + W_CTX, ws + W_ATT);
  k_aw<<<(NROW * S_ + 255) / 256, 256, 0, stream>>>(ws + W_ATT, out + O_AW);
  k_zmatp<<<dim3(4, 40, 8), 128, 0, stream>>>(ws + W_CTX, Wo, bo, sc);
  k_zmatr_ln<<<NROW, 256, 0, stream>>>(sc, r, g1, be1, out + O_EPS, ws + W_Z,
                                       ws + W_OUT1, kk[3][0], kk[3][1]);
  k_ffn1p<<<dim3(16, 20, 4), 128, 0, stream>>>(ws + W_OUT1, W1, b1, sc);
  k_ffn1r<<<1280, 256, 0, stream>>>(sc, ws + W_FFN);
  k_ffn2p<<<dim3(4, 40, 16), 128, 0, stream>>>(ws + W_FFN, W2, sc);
  k_ffn2r_ln<<<NROW, 256, 0, stream>>>(sc, b2, ws + W_OUT1, g3, be3, out + O_OUT3);
  k_zero<<<5000, 256, 0, stream>>>((float4*)(ws + W_PRED));
  k_preds<<<dim3(500, 2, 2), 128, 0, stream>>>(out + O_OUT3, Wout, bout, ws + W_PRED);
  k_stats<<<NROW, 256, 0, stream>>>(ws + W_PRED, x, out + O_W);
  k_it<<<1, 256, 0, stream>>>(out + O_W, (int*)(ws + W_IT), (int*)(ws + W_AMW),
                              kk[4][0], kk[4][1]);
  k_tail<<<2320, 256, 0, stream>>>(ws + W_PRED, out + O_W,
                                   (const int*)(ws + W_AMW), ws + W_Z,
                                   (const int*)(ws + W_IT), I, tp,
                                   out + O_AVG, out + O_MAX,
                                   out + O_Z, out + O_I);
}

// Round 9
// 473.067 us; speedup vs baseline: 1.5165x; 1.5165x over previous
//
#include <hip/hip_runtime.h>
#include <cstdint>
#include <cstddef>

#define B_    16
#define P_    10
#define S_    128
#define D_    512
#define H_    8
#define DH_   64
#define DFF_  2048
#define VOC_  32000
#define NROW  160   // B*P
#define SIGMA 0.05f
#define LN_EPS 1e-6f

// ---------------- Threefry2x32 (bit-exact vs JAX) ----------------
struct U2 { uint32_t x, y; };

__host__ __device__ __forceinline__ U2 tf2x32(uint32_t k0, uint32_t k1,
                                              uint32_t x0, uint32_t x1) {
  uint32_t ks[3] = {k0, k1, k0 ^ k1 ^ 0x1BD11BDAu};
  x0 += ks[0]; x1 += ks[1];
  const int R0[4] = {13, 15, 26, 6};
  const int R1[4] = {17, 29, 16, 24};
#pragma unroll
  for (int i = 0; i < 5; ++i) {
    const int* r = (i & 1) ? R1 : R0;
#pragma unroll
    for (int j = 0; j < 4; ++j) {
      x0 += x1;
      x1 = (x1 << r[j]) | (x1 >> (32 - r[j]));
      x1 ^= x0;
    }
    x0 += ks[(i + 1) % 3];
    x1 += ks[(i + 2) % 3] + (uint32_t)(i + 1);
  }
  return {x0, x1};
}

__device__ __forceinline__ uint32_t jax_bits32(uint32_t k0, uint32_t k1, uint32_t j) {
  U2 o = tf2x32(k0, k1, 0u, j);
  return o.x ^ o.y;
}

__device__ __forceinline__ float erfinv32(float x) {
  float w = -log1pf(-x * x);
  float p;
  if (w < 5.0f) {
    w = w - 2.5f;
    p = 2.81022636e-08f;
    p = fmaf(p, w, 3.43273939e-07f);
    p = fmaf(p, w, -3.5233877e-06f);
    p = fmaf(p, w, -4.39150654e-06f);
    p = fmaf(p, w, 0.00021858087f);
    p = fmaf(p, w, -0.00125372503f);
    p = fmaf(p, w, -0.00417768164f);
    p = fmaf(p, w, 0.246640727f);
    p = fmaf(p, w, 1.50140941f);
  } else {
    w = sqrtf(w) - 3.0f;
    p = -0.000200214257f;
    p = fmaf(p, w, 0.000100950558f);
    p = fmaf(p, w, 0.00134934322f);
    p = fmaf(p, w, -0.00367342844f);
    p = fmaf(p, w, 0.00573950773f);
    p = fmaf(p, w, -0.0076224613f);
    p = fmaf(p, w, 0.00943887047f);
    p = fmaf(p, w, 1.00167406f);
    p = fmaf(p, w, 2.83297682f);
  }
  return p * x;
}

__device__ __forceinline__ float jax_normal(uint32_t k0, uint32_t k1, uint32_t j) {
  uint32_t b = jax_bits32(k0, k1, j);
  float u01 = __uint_as_float((b >> 9) | 0x3F800000u) - 1.0f;
  const float lo = -0.99999994f;
  float u = fmaxf(lo, fmaf(u01, 2.0f, lo));
  return 1.41421356f * erfinv32(u);
}

__device__ __forceinline__ float jax_gumbel(uint32_t k0, uint32_t k1, uint32_t j) {
  uint32_t b = jax_bits32(k0, k1, j);
  float u01 = __uint_as_float((b >> 9) | 0x3F800000u) - 1.0f;
  const float tiny = 1.17549435e-38f;
  float u = fmaxf(tiny, u01 + tiny);
  return -logf(-logf(u));
}

// ---------------- Kernels ----------------

// Gather K,V by particle index I along axis 1
__global__ __launch_bounds__(256) void k_gather(const float* __restrict__ K,
                                                const float* __restrict__ V,
                                                const int* __restrict__ I,
                                                float* __restrict__ oK,
                                                float* __restrict__ oV) {
  size_t idx = (size_t)blockIdx.x * 256 + threadIdx.x;        // float4 index
  const size_t total = (size_t)NROW * S_ * (D_ / 4);
  if (idx >= total) return;
  int d4 = (int)(idx % (D_ / 4));
  size_t row = idx / (D_ / 4);                                 // bp*S + s
  int s = (int)(row % S_);
  int bp = (int)(row / S_);
  int b = bp / P_;
  int iv = I[row];
  size_t src = ((size_t)(b * P_ + iv) * S_ + s) * (D_ / 4) + d4;
  ((float4*)oK)[idx] = ((const float4*)K)[src];
  ((float4*)oV)[idx] = ((const float4*)V)[src];
}

// qkv partial: grid (4 col-chunks, 40 row-tiles, 8 k-chunks of 64), 128 thr.
__global__ __launch_bounds__(128) void k_qkvp(const float* __restrict__ r,
    const float* __restrict__ Wq, const float* __restrict__ bq,
    const float* __restrict__ Wk, const float* __restrict__ bk,
    const float* __restrict__ Wv, const float* __restrict__ bv,
    float* __restrict__ pq, float* __restrict__ pk, float* __restrict__ pv) {
  int c = blockIdx.x * 128 + threadIdx.x;
  int r0 = blockIdx.y * 4;
  int kc = blockIdx.z;
  int d0 = kc * 64;
  float aq[4], ak[4], av[4];
  float bbq = (kc == 0) ? bq[c] : 0.f;
  float bbk = (kc == 0) ? bk[c] : 0.f;
  float bbv = (kc == 0) ? bv[c] : 0.f;
#pragma unroll
  for (int rr = 0; rr < 4; ++rr) { aq[rr] = bbq; ak[rr] = bbk; av[rr] = bbv; }
  for (int d = d0; d < d0 + 64; d += 4) {
    float wq0 = Wq[(size_t)d * D_ + c],      wq1 = Wq[(size_t)(d+1) * D_ + c];
    float wq2 = Wq[(size_t)(d+2) * D_ + c],  wq3 = Wq[(size_t)(d+3) * D_ + c];
    float wk0 = Wk[(size_t)d * D_ + c],      wk1 = Wk[(size_t)(d+1) * D_ + c];
    float wk2 = Wk[(size_t)(d+2) * D_ + c],  wk3 = Wk[(size_t)(d+3) * D_ + c];
    float wv0 = Wv[(size_t)d * D_ + c],      wv1 = Wv[(size_t)(d+1) * D_ + c];
    float wv2 = Wv[(size_t)(d+2) * D_ + c],  wv3 = Wv[(size_t)(d+3) * D_ + c];
#pragma unroll
    for (int rr = 0; rr < 4; ++rr) {
      float4 a = *(const float4*)&r[(size_t)(r0 + rr) * D_ + d];
      aq[rr] = fmaf(a.w, wq3, fmaf(a.z, wq2, fmaf(a.y, wq1, fmaf(a.x, wq0, aq[rr]))));
      ak[rr] = fmaf(a.w, wk3, fmaf(a.z, wk2, fmaf(a.y, wk1, fmaf(a.x, wk0, ak[rr]))));
      av[rr] = fmaf(a.w, wv3, fmaf(a.z, wv2, fmaf(a.y, wv1, fmaf(a.x, wv0, av[rr]))));
    }
  }
#pragma unroll
  for (int rr = 0; rr < 4; ++rr) {
    size_t o = ((size_t)kc * NROW + r0 + rr) * D_ + c;
    pq[o] = aq[rr]; pk[o] = ak[rr]; pv[o] = av[rr];
  }
}

// qkv reduce: sum 8 partials (ascending), add noise, scatter K/V at ts.
__global__ __launch_bounds__(256) void k_qkvr(const float* __restrict__ pq,
    const float* __restrict__ pk, const float* __restrict__ pv,
    const int* __restrict__ tptr, float* __restrict__ wsq,
    float* __restrict__ oK, float* __restrict__ oV,
    uint32_t k1a, uint32_t k1b, uint32_t k2a, uint32_t k2b,
    uint32_t k3a, uint32_t k3b) {
  int idx = blockIdx.x * 256 + threadIdx.x;
  if (idx >= NROW * D_) return;
  float q = pq[idx], k = pk[idx], v = pv[idx];
#pragma unroll
  for (int kc = 1; kc < 8; ++kc) {
    size_t o = (size_t)kc * (NROW * D_) + idx;
    q += pq[o]; k += pk[o]; v += pv[o];
  }
  int bp = idx / D_, c = idx % D_;
  int ts = min(max(*tptr, 0), S_ - 1);
  uint32_t j = (uint32_t)idx;
  wsq[idx] = q + SIGMA * jax_normal(k1a, k1b, j);
  oK[((size_t)bp * S_ + ts) * D_ + c] = k + SIGMA * jax_normal(k2a, k2b, j);
  oV[((size_t)bp * S_ + ts) * D_ + c] = v + SIGMA * jax_normal(k3a, k3b, j);
}

// attention: one block per (bp, h); 128 threads (one per s).
// PV uses all 128 lanes: two s-halves, LDS combine.
__global__ __launch_bounds__(128) void k_attn(const float* __restrict__ wsq,
    const float* __restrict__ oK, const float* __restrict__ oV,
    float* __restrict__ wsctx, float* __restrict__ wsattn) {
  __shared__ float s_q[DH_];
  __shared__ float s_attn[S_];
  __shared__ float red[S_];
  int bp = blockIdx.x >> 3, h = blockIdx.x & 7, tid = threadIdx.x;
  if (tid < DH_) s_q[tid] = wsq[bp * D_ + h * DH_ + tid];
  __syncthreads();
  const float4* krow = (const float4*)(oK + ((size_t)bp * S_ + tid) * D_ + h * DH_);
  const float4* q4 = (const float4*)s_q;
  float sc = 0.f;
#pragma unroll
  for (int d = 0; d < DH_ / 4; ++d) {
    float4 kv = krow[d], qv = q4[d];
    sc += qv.x * kv.x + qv.y * kv.y + qv.z * kv.z + qv.w * kv.w;
  }
  sc *= 0.125f;  // 1/sqrt(64)
  red[tid] = sc; __syncthreads();
  for (int s = 64; s > 0; s >>= 1) {
    if (tid < s) red[tid] = fmaxf(red[tid], red[tid + s]);
    __syncthreads();
  }
  float m = red[0]; __syncthreads();
  float e = expf(sc - m);
  red[tid] = e; __syncthreads();
  for (int s = 64; s > 0; s >>= 1) {
    if (tid < s) red[tid] += red[tid + s];
    __syncthreads();
  }
  float a = e / red[0];
  s_attn[tid] = a;
  wsattn[(size_t)blockIdx.x * S_ + tid] = a;
  __syncthreads();
  {
    int dd = tid & 63, sh = tid >> 6;   // sh in {0,1}: s-half
    const float* vb = oV + ((size_t)bp * S_ + sh * 64) * D_ + h * DH_ + dd;
    float acc = 0.f;
#pragma unroll 4
    for (int s = 0; s < 64; ++s) acc = fmaf(s_attn[sh * 64 + s], vb[(size_t)s * D_], acc);
    red[tid] = acc; __syncthreads();
    if (tid < DH_) wsctx[bp * D_ + h * DH_ + tid] = red[tid] + red[tid + 64];
  }
}

// attn_weights = mean over heads
__global__ __launch_bounds__(256) void k_aw(const float* __restrict__ wsattn,
                                            float* __restrict__ oaw) {
  int idx = blockIdx.x * 256 + threadIdx.x;
  if (idx >= NROW * S_) return;
  int bp = idx / S_, s = idx % S_;
  float acc = 0.f;
#pragma unroll
  for (int h = 0; h < H_; ++h) acc += wsattn[(size_t)(bp * H_ + h) * S_ + s];
  oaw[idx] = acc * 0.125f;
}

// zmat partial: grid (4, 40, 8 k-chunks of 64), 128 thr.  kc==0 carries bias.
__global__ __launch_bounds__(128) void k_zmatp(const float* __restrict__ wsctx,
    const float* __restrict__ Wo, const float* __restrict__ bo,
    float* __restrict__ pz) {
  int c = blockIdx.x * 128 + threadIdx.x;
  int r0 = blockIdx.y * 4;
  int kc = blockIdx.z;
  int d0 = kc * 64;
  float acc[4];
  float bb = (kc == 0) ? bo[c] : 0.f;
#pragma unroll
  for (int rr = 0; rr < 4; ++rr) acc[rr] = bb;
  for (int d = d0; d < d0 + 64; d += 4) {
    float w0 = Wo[(size_t)d * D_ + c],     w1 = Wo[(size_t)(d+1) * D_ + c];
    float w2 = Wo[(size_t)(d+2) * D_ + c], w3 = Wo[(size_t)(d+3) * D_ + c];
#pragma unroll
    for (int rr = 0; rr < 4; ++rr) {
      float4 a = *(const float4*)&wsctx[(size_t)(r0 + rr) * D_ + d];
      acc[rr] = fmaf(a.w, w3, fmaf(a.z, w2, fmaf(a.y, w1, fmaf(a.x, w0, acc[rr]))));
    }
  }
#pragma unroll
  for (int rr = 0; rr < 4; ++rr)
    pz[((size_t)kc * NROW + r0 + rr) * D_ + c] = acc[rr];
}

// FUSED zmat-reduce + LN1: one block per row (160 blocks, 256 thr, 2 elem/thr).
__global__ __launch_bounds__(256) void k_zmatr_ln(const float* __restrict__ pz,
    const float* __restrict__ r, const float* __restrict__ g,
    const float* __restrict__ b, float* __restrict__ oeps,
    float* __restrict__ wsz, float* __restrict__ o,
    uint32_t k4a, uint32_t k4b) {
  __shared__ float red[256];
  int bp = blockIdx.x, tid = threadIdx.x;
  float x0, x1;
  {
    int idx = bp * D_ + tid;
    float s = pz[idx];
#pragma unroll
    for (int kc = 1; kc < 8; ++kc) s += pz[(size_t)kc * (NROW * D_) + idx];
    float eps = SIGMA * jax_normal(k4a, k4b, (uint32_t)idx);
    oeps[idx] = eps;
    float z = s + eps;
    wsz[idx] = z;
    x0 = z + r[idx];
  }
  {
    int idx = bp * D_ + tid + 256;
    float s = pz[idx];
#pragma unroll
    for (int kc = 1; kc < 8; ++kc) s += pz[(size_t)kc * (NROW * D_) + idx];
    float eps = SIGMA * jax_normal(k4a, k4b, (uint32_t)idx);
    oeps[idx] = eps;
    float z = s + eps;
    wsz[idx] = z;
    x1 = z + r[idx];
  }
  red[tid] = x0 + x1; __syncthreads();
  for (int s = 128; s > 0; s >>= 1) { if (tid < s) red[tid] += red[tid + s]; __syncthreads(); }
  float mu = red[0] / (float)D_; __syncthreads();
  float d0 = x0 - mu, d1 = x1 - mu;
  red[tid] = d0 * d0 + d1 * d1; __syncthreads();
  for (int s = 128; s > 0; s >>= 1) { if (tid < s) red[tid] += red[tid + s]; __syncthreads(); }
  float inv = 1.0f / sqrtf(red[0] / (float)D_ + LN_EPS);
  o[bp * D_ + tid] = g[tid] * d0 * inv + b[tid];
  o[bp * D_ + tid + 256] = g[tid + 256] * d1 * inv + b[tid + 256];
}

// ffn1 partial: grid (16, 20, 4 k-chunks of 128), 128 thr.  kc==0 carries b1.
__global__ __launch_bounds__(128) void k_ffn1p(const float* __restrict__ wsout1,
    const float* __restrict__ W1, const float* __restrict__ b1,
    float* __restrict__ pf) {
  int c = blockIdx.x * 128 + threadIdx.x;
  int r0 = blockIdx.y * 8;
  int kc = blockIdx.z;
  int d0 = kc * 128;
  float acc[8];
  float bb = (kc == 0) ? b1[c] : 0.f;
#pragma unroll
  for (int rr = 0; rr < 8; ++rr) acc[rr] = bb;
  for (int d = d0; d < d0 + 128; d += 4) {
    float w0 = W1[(size_t)d * DFF_ + c],     w1 = W1[(size_t)(d+1) * DFF_ + c];
    float w2 = W1[(size_t)(d+2) * DFF_ + c], w3 = W1[(size_t)(d+3) * DFF_ + c];
#pragma unroll
    for (int rr = 0; rr < 8; ++rr) {
      float4 a = *(const float4*)&wsout1[(size_t)(r0 + rr) * D_ + d];
      acc[rr] = fmaf(a.w, w3, fmaf(a.z, w2, fmaf(a.y, w1, fmaf(a.x, w0, acc[rr]))));
    }
  }
#pragma unroll
  for (int rr = 0; rr < 8; ++rr)
    pf[((size_t)kc * NROW + r0 + rr) * DFF_ + c] = acc[rr];
}

// ffn1 reduce + relu
__global__ __launch_bounds__(256) void k_ffn1r(const float* __restrict__ pf,
    float* __restrict__ wsffn) {
  int idx = blockIdx.x * 256 + threadIdx.x;
  if (idx >= NROW * DFF_) return;
  float s = pf[idx];
#pragma unroll
  for (int kc = 1; kc < 4; ++kc) s += pf[(size_t)kc * (NROW * DFF_) + idx];
  wsffn[idx] = fmaxf(s, 0.f);
}

// ffn2 partial: grid (4, 40, 16 k-chunks of 128), 128 thr.
__global__ __launch_bounds__(128) void k_ffn2p(const float* __restrict__ wsffn,
    const float* __restrict__ W2, float* __restrict__ p2) {
  int c = blockIdx.x * 128 + threadIdx.x;
  int r0 = blockIdx.y * 4;
  int kc = blockIdx.z;
  int d0 = kc * 128;
  float acc[4];
#pragma unroll
  for (int rr = 0; rr < 4; ++rr) acc[rr] = 0.f;
  for (int d = d0; d < d0 + 128; d += 4) {
    float w0 = W2[(size_t)d * D_ + c],     w1 = W2[(size_t)(d+1) * D_ + c];
    float w2 = W2[(size_t)(d+2) * D_ + c], w3 = W2[(size_t)(d+3) * D_ + c];
#pragma unroll
    for (int rr = 0; rr < 4; ++rr) {
      float4 a = *(const float4*)&wsffn[(size_t)(r0 + rr) * DFF_ + d];
      acc[rr] = fmaf(a.w, w3, fmaf(a.z, w2, fmaf(a.y, w1, fmaf(a.x, w0, acc[rr]))));
    }
  }
#pragma unroll
  for (int rr = 0; rr < 4; ++rr)
    p2[((size_t)kc * NROW + r0 + rr) * D_ + c] = acc[rr];
}

// FUSED ffn2-reduce + LN3: writes out3 directly.
__global__ __launch_bounds__(256) void k_ffn2r_ln(const float* __restrict__ p2,
    const float* __restrict__ b2, const float* __restrict__ wsout1,
    const float* __restrict__ g, const float* __restrict__ b,
    float* __restrict__ o) {
  __shared__ float red[256];
  int bp = blockIdx.x, tid = threadIdx.x;
  float x0, x1;
  {
    int idx = bp * D_ + tid;
    float s = p2[idx];
#pragma unroll
    for (int kc = 1; kc < 16; ++kc) s += p2[(size_t)kc * (NROW * D_) + idx];
    x0 = s + b2[tid] + wsout1[idx];
  }
  {
    int idx = bp * D_ + tid + 256;
    float s = p2[idx];
#pragma unroll
    for (int kc = 1; kc < 16; ++kc) s += p2[(size_t)kc * (NROW * D_) + idx];
    x1 = s + b2[tid + 256] + wsout1[idx];
  }
  red[tid] = x0 + x1; __syncthreads();
  for (int s = 128; s > 0; s >>= 1) { if (tid < s) red[tid] += red[tid + s]; __syncthreads(); }
  float mu = red[0] / (float)D_; __syncthreads();
  float d0 = x0 - mu, d1 = x1 - mu;
  red[tid] = d0 * d0 + d1 * d1; __syncthreads();
  for (int s = 128; s > 0; s >>= 1) { if (tid < s) red[tid] += red[tid + s]; __syncthreads(); }
  float inv = 1.0f / sqrtf(red[0] / (float)D_ + LN_EPS);
  o[bp * D_ + tid] = g[tid] * d0 * inv + b[tid];
  o[bp * D_ + tid + 256] = g[tid + 256] * d1 * inv + b[tid + 256];
}

// predictions = out3 @ Wout + bout  (160 x 512 x 32000)
// TRAFFIC-HALVED SHAPE: per-thread tile 10 rows x 4 cols (40 acc).  Total
// W VMEM traffic = 10.5GB / r_t: all prior variants had r_t=5 -> 2.1 GB
// (16x intra-block W duplication), a ~55-60us L1/L2 service floor that
// explains the 111us plateau; r_t=10 -> 1.05 GB, FMA:W-load ratio 160:4
// per dd-step (was 80:4).  Inner loop form identical to the proven R2
// variant (JIT W loads, plain stores, bias head, d ascending) -> bit-exact.
// Block: 128 thr (16 cg x 8 rg), 80 rows x 64 cols; grid (500, 2).
// LDS [80][68] = 21.8 KB -> ~7 blocks/CU at ~75 VGPR (launch_bounds(128,4)).
// No atomics (R7 lesson), no held prefetch regs (R4/R6), no team sync (R5).
__global__ __launch_bounds__(128, 4) void k_preds(const float* __restrict__ A,
    const float* __restrict__ Wout, const float* __restrict__ bout,
    float* __restrict__ wspred) {
  __shared__ float sA[80][68];   // 21.76 KB
  int tid = threadIdx.x;
  int cb = blockIdx.x, rh = blockIdx.y;
  int cg = tid & 15, rg = tid >> 4;   // 16 cg x 4 cols; 8 rg x 10 rows
  int c = cb * 64 + cg * 4;
  const float* Ab = A + (size_t)rh * 80 * D_;
  const float* Wp = Wout + c;
  float4 acc[10];
  {
    float4 b0 = *(const float4*)&bout[c];
#pragma unroll
    for (int i = 0; i < 10; ++i) acc[i] = b0;
  }
  for (int t = 0; t < 8; ++t) {
    int d0 = t * 64;
    if (t) __syncthreads();          // previous chunk's reads done
    // stage A[0:80][d0:d0+64]: 1280 float4, 10 per thread, coalesced
#pragma unroll
    for (int k = 0; k < 10; ++k) {
      int idx = tid + k * 128;
      int row = idx >> 4, c4 = idx & 15;
      *(float4*)&sA[row][c4 * 4] =
          *(const float4*)&Ab[(size_t)row * D_ + d0 + c4 * 4];
    }
    __syncthreads();
#pragma unroll 2
    for (int dd = 0; dd < 64; dd += 4) {
      size_t wb = (size_t)(d0 + dd) * VOC_;
      float4 w0 = *(const float4*)&Wp[wb];
      float4 w1 = *(const float4*)&Wp[wb + VOC_];
      float4 w2 = *(const float4*)&Wp[wb + 2 * (size_t)VOC_];
      float4 w3 = *(const float4*)&Wp[wb + 3 * (size_t)VOC_];
#pragma unroll
      for (int i = 0; i < 10; ++i) {
        float4 a = *(const float4*)&sA[rg * 10 + i][dd];
        acc[i].x = fmaf(a.x, w0.x, acc[i].x); acc[i].y = fmaf(a.x, w0.y, acc[i].y);
        acc[i].z = fmaf(a.x, w0.z, acc[i].z); acc[i].w = fmaf(a.x, w0.w, acc[i].w);
        acc[i].x = fmaf(a.y, w1.x, acc[i].x); acc[i].y = fmaf(a.y, w1.y, acc[i].y);
        acc[i].z = fmaf(a.y, w1.z, acc[i].z); acc[i].w = fmaf(a.y, w1.w, acc[i].w);
        acc[i].x = fmaf(a.z, w2.x, acc[i].x); acc[i].y = fmaf(a.z, w2.y, acc[i].y);
        acc[i].z = fmaf(a.z, w2.z, acc[i].z); acc[i].w = fmaf(a.z, w2.w, acc[i].w);
        acc[i].x = fmaf(a.w, w3.x, acc[i].x); acc[i].y = fmaf(a.w, w3.y, acc[i].y);
        acc[i].z = fmaf(a.w, w3.z, acc[i].z); acc[i].w = fmaf(a.w, w3.w, acc[i].w);
      }
    }
  }
#pragma unroll
  for (int i = 0; i < 10; ++i) {
    size_t o = (size_t)(rh * 80 + rg * 10 + i) * VOC_ + c;
    *(float4*)&wspred[o] = acc[i];
  }
}

// per-row softmax stats over VOC; w[b,p] = probs at x[b]
__global__ __launch_bounds__(256) void k_stats(const float* __restrict__ wspred,
    const int* __restrict__ x, float* __restrict__ ow) {
  __shared__ float red[256];
  int bp = blockIdx.x, tid = threadIdx.x;
  const float* row = wspred + (size_t)bp * VOC_;
  const float4* row4 = (const float4*)row;
  float m = -INFINITY;
  for (int i = tid; i < VOC_ / 4; i += 256) {
    float4 v = row4[i];
    m = fmaxf(m, fmaxf(fmaxf(v.x, v.y), fmaxf(v.z, v.w)));
  }
  red[tid] = m; __syncthreads();
  for (int s = 128; s > 0; s >>= 1) { if (tid < s) red[tid] = fmaxf(red[tid], red[tid + s]); __syncthreads(); }
  m = red[0]; __syncthreads();
  float sum = 0.f;
  for (int i = tid; i < VOC_ / 4; i += 256) {
    float4 v = row4[i];
    sum += expf(v.x - m) + expf(v.y - m) + expf(v.z - m) + expf(v.w - m);
  }
  red[tid] = sum; __syncthreads();
  for (int s = 128; s > 0; s >>= 1) { if (tid < s) red[tid] += red[tid + s]; __syncthreads(); }
  if (tid == 0) {
    int b = bp / P_;
    ow[bp] = expf(row[x[b]] - m) / red[0];
  }
}

// i_t via gumbel-argmax; argmax_w per batch
__global__ __launch_bounds__(256) void k_it(const float* __restrict__ ow,
    int* __restrict__ wsit, int* __restrict__ wsamw,
    uint32_t k5a, uint32_t k5b) {
  int tid = threadIdx.x;
  if (tid < NROW) {
    int b = tid / P_;
    float best = -INFINITY; int bi = 0;
#pragma unroll
    for (int i = 0; i < P_; ++i) {
      float g = jax_gumbel(k5a, k5b, (uint32_t)(tid * P_ + i));
      float v = g + ow[b * P_ + i];
      if (v > best) { best = v; bi = i; }
    }
    wsit[tid] = bi;
  }
  if (tid < B_) {
    float best = -INFINITY; int bi = 0;
#pragma unroll
    for (int p = 0; p < P_; ++p) {
      float v = ow[tid * P_ + p];
      if (v > best) { best = v; bi = p; }
    }
    wsamw[tid] = bi;
  }
}

// MERGED tail: blocks [0,2000) = avgmax; blocks [2000,2320) = zsel+I_new.
__global__ __launch_bounds__(256) void k_tail(const float* __restrict__ wspred,
    const float* __restrict__ ow, const int* __restrict__ wsamw,
    const float* __restrict__ wsz, const int* __restrict__ wsit,
    const int* __restrict__ I, const int* __restrict__ tptr,
    float* __restrict__ oavg, float* __restrict__ omax,
    float* __restrict__ oz, float* __restrict__ oI) {
  int bid = blockIdx.x, tid = threadIdx.x;
  if (bid < 2000) {
    int idx = bid * 256 + tid;
    if (idx >= B_ * VOC_) return;
    int b = idx / VOC_, c = idx % VOC_;
    float acc = 0.f;
#pragma unroll
    for (int p = 0; p < P_; ++p)
      acc = fmaf(wspred[(size_t)(b * P_ + p) * VOC_ + c], ow[b * P_ + p], acc);
    oavg[idx] = acc;
    omax[idx] = wspred[(size_t)(b * P_ + wsamw[b]) * VOC_ + c];
  } else {
    int idx = (bid - 2000) * 256 + tid;
    if (idx < NROW * D_) {
      int bp = idx / D_, d = idx % D_;
      int b = bp / P_;
      oz[idx] = wsz[(size_t)(b * P_ + wsit[bp]) * D_ + d];
    }
    if (idx < NROW * S_) {
      int bp = idx / S_, s = idx % S_;
      int ts = min(max(*tptr, 0), S_ - 1);
      oI[idx] = (s == ts) ? (float)wsit[bp] : (float)I[idx];
    }
  }
}

// ---------------- Host launch ----------------
static void derive_keys(uint32_t keys[5][2]) {
  for (int i = 0; i < 5; ++i) {
    U2 o = tf2x32(0u, 42u, 0u, (uint32_t)i);
    keys[i][0] = o.x; keys[i][1] = o.y;
  }
}

extern "C" void kernel_launch(void* const* d_in, const int* in_sizes, int n_in,
                              void* d_out, int out_size, void* d_ws, size_t ws_size,
                              hipStream_t stream) {
  const float* r   = (const float*)d_in[0];
  const int*   x   = (const int*)d_in[1];
  const float* K   = (const float*)d_in[2];
  const float* V   = (const float*)d_in[3];
  const int*   I   = (const int*)d_in[5];
  const int*   tp  = (const int*)d_in[6];
  const float* Wq  = (const float*)d_in[7];
  const float* bq  = (const float*)d_in[8];
  const float* Wk  = (const float*)d_in[9];
  const float* bk  = (const float*)d_in[10];
  const float* Wv  = (const float*)d_in[11];
  const float* bv  = (const float*)d_in[12];
  const float* Wo  = (const float*)d_in[13];
  const float* bo  = (const float*)d_in[14];
  const float* W1  = (const float*)d_in[15];
  const float* b1  = (const float*)d_in[16];
  const float* W2  = (const float*)d_in[17];
  const float* b2  = (const float*)d_in[18];
  const float* g1  = (const float*)d_in[19];
  const float* be1 = (const float*)d_in[20];
  const float* g3  = (const float*)d_in[21];
  const float* be3 = (const float*)d_in[22];
  const float* Wout = (const float*)d_in[23];
  const float* bout = (const float*)d_in[24];

  float* out = (float*)d_out;
  const size_t O_OUT3 = 0;
  const size_t O_Z    = 81920;
  const size_t O_AVG  = 163840;
  const size_t O_MAX  = 675840;
  const size_t O_EPS  = 1187840;
  const size_t O_AW   = 1269760;
  const size_t O_K    = 1290240;
  const size_t O_V    = 11776000;
  const size_t O_W    = 22261760;
  const size_t O_I    = 22261920;

  float* ws = (float*)d_ws;
  const size_t W_Q    = 0;
  const size_t W_CTX  = 81920;
  const size_t W_Z    = 163840;
  const size_t W_OUT1 = 245760;
  const size_t W_ATT  = 327680;   // 163840
  const size_t W_FFN  = 491520;   // 327680
  const size_t W_PRED = 819200;   // 5120000 -- also reused as K-split scratch
  const size_t W_IT   = 5939200;
  const size_t W_AMW  = 5939360;

  uint32_t kk[5][2];
  derive_keys(kk);

  float* oK = out + O_K;
  float* oV = out + O_V;
  float* sc = ws + W_PRED;        // K-split partial scratch (dead before k_preds)

  k_gather<<<10240, 256, 0, stream>>>(K, V, I, oK, oV);
  k_qkvp<<<dim3(4, 40, 8), 128, 0, stream>>>(r, Wq, bq, Wk, bk, Wv, bv,
                                             sc, sc + 655360, sc + 1310720);
  k_qkvr<<<320, 256, 0, stream>>>(sc, sc + 655360, sc + 1310720, tp,
                                  ws + W_Q, oK, oV,
                                  kk[0][0], kk[0][1], kk[1][0], kk[1][1],
                                  kk[2][0], kk[2][1]);
  k_attn<<<NROW * H_, 128, 0, stream>>>(ws + W_Q, oK, oV, ws + W_CTX, ws + W_ATT);
  k_aw<<<(NROW * S_ + 255) / 256, 256, 0, stream>>>(ws + W_ATT, out + O_AW);
  k_zmatp<<<dim3(4, 40, 8), 128, 0, stream>>>(ws + W_CTX, Wo, bo, sc);
  k_zmatr_ln<<<NROW, 256, 0, stream>>>(sc, r, g1, be1, out + O_EPS, ws + W_Z,
                                       ws + W_OUT1, kk[3][0], kk[3][1]);
  k_ffn1p<<<dim3(16, 20, 4), 128, 0, stream>>>(ws + W_OUT1, W1, b1, sc);
  k_ffn1r<<<1280, 256, 0, stream>>>(sc, ws + W_FFN);
  k_ffn2p<<<dim3(4, 40, 16), 128, 0, stream>>>(ws + W_FFN, W2, sc);
  k_ffn2r_ln<<<NROW, 256, 0, stream>>>(sc, b2, ws + W_OUT1, g3, be3, out + O_OUT3);
  k_preds<<<dim3(500, 2), 128, 0, stream>>>(out + O_OUT3, Wout, bout, ws + W_PRED);
  k_stats<<<NROW, 256, 0, stream>>>(ws + W_PRED, x, out + O_W);
  k_it<<<1, 256, 0, stream>>>(out + O_W, (int*)(ws + W_IT), (int*)(ws + W_AMW),
                              kk[4][0], kk[4][1]);
  k_tail<<<2320, 256, 0, stream>>>(ws + W_PRED, out + O_W,
                                   (const int*)(ws + W_AMW), ws + W_Z,
                                   (const int*)(ws + W_IT), I, tp,
                                   out + O_AVG, out + O_MAX,
                                   out + O_Z, out + O_I);
}

// Round 10
// 438.547 us; speedup vs baseline: 1.6359x; 1.0787x over previous
//
#include <hip/hip_runtime.h>
#include <cstdint>
#include <cstddef>

#define B_    16
#define P_    10
#define S_    128
#define D_    512
#define H_    8
#define DH_   64
#define DFF_  2048
#define VOC_  32000
#define NROW  160   // B*P
#define SIGMA 0.05f
#define LN_EPS 1e-6f

// ---------------- Threefry2x32 (bit-exact vs JAX) ----------------
struct U2 { uint32_t x, y; };

__host__ __device__ __forceinline__ U2 tf2x32(uint32_t k0, uint32_t k1,
                                              uint32_t x0, uint32_t x1) {
  uint32_t ks[3] = {k0, k1, k0 ^ k1 ^ 0x1BD11BDAu};
  x0 += ks[0]; x1 += ks[1];
  const int R0[4] = {13, 15, 26, 6};
  const int R1[4] = {17, 29, 16, 24};
#pragma unroll
  for (int i = 0; i < 5; ++i) {
    const int* r = (i & 1) ? R1 : R0;
#pragma unroll
    for (int j = 0; j < 4; ++j) {
      x0 += x1;
      x1 = (x1 << r[j]) | (x1 >> (32 - r[j]));
      x1 ^= x0;
    }
    x0 += ks[(i + 1) % 3];
    x1 += ks[(i + 2) % 3] + (uint32_t)(i + 1);
  }
  return {x0, x1};
}

__device__ __forceinline__ uint32_t jax_bits32(uint32_t k0, uint32_t k1, uint32_t j) {
  U2 o = tf2x32(k0, k1, 0u, j);
  return o.x ^ o.y;
}

__device__ __forceinline__ float erfinv32(float x) {
  float w = -log1pf(-x * x);
  float p;
  if (w < 5.0f) {
    w = w - 2.5f;
    p = 2.81022636e-08f;
    p = fmaf(p, w, 3.43273939e-07f);
    p = fmaf(p, w, -3.5233877e-06f);
    p = fmaf(p, w, -4.39150654e-06f);
    p = fmaf(p, w, 0.00021858087f);
    p = fmaf(p, w, -0.00125372503f);
    p = fmaf(p, w, -0.00417768164f);
    p = fmaf(p, w, 0.246640727f);
    p = fmaf(p, w, 1.50140941f);
  } else {
    w = sqrtf(w) - 3.0f;
    p = -0.000200214257f;
    p = fmaf(p, w, 0.000100950558f);
    p = fmaf(p, w, 0.00134934322f);
    p = fmaf(p, w, -0.00367342844f);
    p = fmaf(p, w, 0.00573950773f);
    p = fmaf(p, w, -0.0076224613f);
    p = fmaf(p, w, 0.00943887047f);
    p = fmaf(p, w, 1.00167406f);
    p = fmaf(p, w, 2.83297682f);
  }
  return p * x;
}

__device__ __forceinline__ float jax_normal(uint32_t k0, uint32_t k1, uint32_t j) {
  uint32_t b = jax_bits32(k0, k1, j);
  float u01 = __uint_as_float((b >> 9) | 0x3F800000u) - 1.0f;
  const float lo = -0.99999994f;
  float u = fmaxf(lo, fmaf(u01, 2.0f, lo));
  return 1.41421356f * erfinv32(u);
}

__device__ __forceinline__ float jax_gumbel(uint32_t k0, uint32_t k1, uint32_t j) {
  uint32_t b = jax_bits32(k0, k1, j);
  float u01 = __uint_as_float((b >> 9) | 0x3F800000u) - 1.0f;
  const float tiny = 1.17549435e-38f;
  float u = fmaxf(tiny, u01 + tiny);
  return -logf(-logf(u));
}

// ---------------- Kernels ----------------

// Gather K,V by particle index I along axis 1
__global__ __launch_bounds__(256) void k_gather(const float* __restrict__ K,
                                                const float* __restrict__ V,
                                                const int* __restrict__ I,
                                                float* __restrict__ oK,
                                                float* __restrict__ oV) {
  size_t idx = (size_t)blockIdx.x * 256 + threadIdx.x;        // float4 index
  const size_t total = (size_t)NROW * S_ * (D_ / 4);
  if (idx >= total) return;
  int d4 = (int)(idx % (D_ / 4));
  size_t row = idx / (D_ / 4);                                 // bp*S + s
  int s = (int)(row % S_);
  int bp = (int)(row / S_);
  int b = bp / P_;
  int iv = I[row];
  size_t src = ((size_t)(b * P_ + iv) * S_ + s) * (D_ / 4) + d4;
  ((float4*)oK)[idx] = ((const float4*)K)[src];
  ((float4*)oV)[idx] = ((const float4*)V)[src];
}

// qkv partial: grid (4 col-chunks, 40 row-tiles, 8 k-chunks of 64), 128 thr.
__global__ __launch_bounds__(128) void k_qkvp(const float* __restrict__ r,
    const float* __restrict__ Wq, const float* __restrict__ bq,
    const float* __restrict__ Wk, const float* __restrict__ bk,
    const float* __restrict__ Wv, const float* __restrict__ bv,
    float* __restrict__ pq, float* __restrict__ pk, float* __restrict__ pv) {
  int c = blockIdx.x * 128 + threadIdx.x;
  int r0 = blockIdx.y * 4;
  int kc = blockIdx.z;
  int d0 = kc * 64;
  float aq[4], ak[4], av[4];
  float bbq = (kc == 0) ? bq[c] : 0.f;
  float bbk = (kc == 0) ? bk[c] : 0.f;
  float bbv = (kc == 0) ? bv[c] : 0.f;
#pragma unroll
  for (int rr = 0; rr < 4; ++rr) { aq[rr] = bbq; ak[rr] = bbk; av[rr] = bbv; }
  for (int d = d0; d < d0 + 64; d += 4) {
    float wq0 = Wq[(size_t)d * D_ + c],      wq1 = Wq[(size_t)(d+1) * D_ + c];
    float wq2 = Wq[(size_t)(d+2) * D_ + c],  wq3 = Wq[(size_t)(d+3) * D_ + c];
    float wk0 = Wk[(size_t)d * D_ + c],      wk1 = Wk[(size_t)(d+1) * D_ + c];
    float wk2 = Wk[(size_t)(d+2) * D_ + c],  wk3 = Wk[(size_t)(d+3) * D_ + c];
    float wv0 = Wv[(size_t)d * D_ + c],      wv1 = Wv[(size_t)(d+1) * D_ + c];
    float wv2 = Wv[(size_t)(d+2) * D_ + c],  wv3 = Wv[(size_t)(d+3) * D_ + c];
#pragma unroll
    for (int rr = 0; rr < 4; ++rr) {
      float4 a = *(const float4*)&r[(size_t)(r0 + rr) * D_ + d];
      aq[rr] = fmaf(a.w, wq3, fmaf(a.z, wq2, fmaf(a.y, wq1, fmaf(a.x, wq0, aq[rr]))));
      ak[rr] = fmaf(a.w, wk3, fmaf(a.z, wk2, fmaf(a.y, wk1, fmaf(a.x, wk0, ak[rr]))));
      av[rr] = fmaf(a.w, wv3, fmaf(a.z, wv2, fmaf(a.y, wv1, fmaf(a.x, wv0, av[rr]))));
    }
  }
#pragma unroll
  for (int rr = 0; rr < 4; ++rr) {
    size_t o = ((size_t)kc * NROW + r0 + rr) * D_ + c;
    pq[o] = aq[rr]; pk[o] = ak[rr]; pv[o] = av[rr];
  }
}

// qkv reduce: sum 8 partials (ascending), add noise, scatter K/V at ts.
__global__ __launch_bounds__(256) void k_qkvr(const float* __restrict__ pq,
    const float* __restrict__ pk, const float* __restrict__ pv,
    const int* __restrict__ tptr, float* __restrict__ wsq,
    float* __restrict__ oK, float* __restrict__ oV,
    uint32_t k1a, uint32_t k1b, uint32_t k2a, uint32_t k2b,
    uint32_t k3a, uint32_t k3b) {
  int idx = blockIdx.x * 256 + threadIdx.x;
  if (idx >= NROW * D_) return;
  float q = pq[idx], k = pk[idx], v = pv[idx];
#pragma unroll
  for (int kc = 1; kc < 8; ++kc) {
    size_t o = (size_t)kc * (NROW * D_) + idx;
    q += pq[o]; k += pk[o]; v += pv[o];
  }
  int bp = idx / D_, c = idx % D_;
  int ts = min(max(*tptr, 0), S_ - 1);
  uint32_t j = (uint32_t)idx;
  wsq[idx] = q + SIGMA * jax_normal(k1a, k1b, j);
  oK[((size_t)bp * S_ + ts) * D_ + c] = k + SIGMA * jax_normal(k2a, k2b, j);
  oV[((size_t)bp * S_ + ts) * D_ + c] = v + SIGMA * jax_normal(k3a, k3b, j);
}

// attention: one block per (bp, h); 128 threads (one per s).
// PV uses all 128 lanes: two s-halves, LDS combine.
__global__ __launch_bounds__(128) void k_attn(const float* __restrict__ wsq,
    const float* __restrict__ oK, const float* __restrict__ oV,
    float* __restrict__ wsctx, float* __restrict__ wsattn) {
  __shared__ float s_q[DH_];
  __shared__ float s_attn[S_];
  __shared__ float red[S_];
  int bp = blockIdx.x >> 3, h = blockIdx.x & 7, tid = threadIdx.x;
  if (tid < DH_) s_q[tid] = wsq[bp * D_ + h * DH_ + tid];
  __syncthreads();
  const float4* krow = (const float4*)(oK + ((size_t)bp * S_ + tid) * D_ + h * DH_);
  const float4* q4 = (const float4*)s_q;
  float sc = 0.f;
#pragma unroll
  for (int d = 0; d < DH_ / 4; ++d) {
    float4 kv = krow[d], qv = q4[d];
    sc += qv.x * kv.x + qv.y * kv.y + qv.z * kv.z + qv.w * kv.w;
  }
  sc *= 0.125f;  // 1/sqrt(64)
  red[tid] = sc; __syncthreads();
  for (int s = 64; s > 0; s >>= 1) {
    if (tid < s) red[tid] = fmaxf(red[tid], red[tid + s]);
    __syncthreads();
  }
  float m = red[0]; __syncthreads();
  float e = expf(sc - m);
  red[tid] = e; __syncthreads();
  for (int s = 64; s > 0; s >>= 1) {
    if (tid < s) red[tid] += red[tid + s];
    __syncthreads();
  }
  float a = e / red[0];
  s_attn[tid] = a;
  wsattn[(size_t)blockIdx.x * S_ + tid] = a;
  __syncthreads();
  {
    int dd = tid & 63, sh = tid >> 6;   // sh in {0,1}: s-half
    const float* vb = oV + ((size_t)bp * S_ + sh * 64) * D_ + h * DH_ + dd;
    float acc = 0.f;
#pragma unroll 4
    for (int s = 0; s < 64; ++s) acc = fmaf(s_attn[sh * 64 + s], vb[(size_t)s * D_], acc);
    red[tid] = acc; __syncthreads();
    if (tid < DH_) wsctx[bp * D_ + h * DH_ + tid] = red[tid] + red[tid + 64];
  }
}

// attn_weights = mean over heads
__global__ __launch_bounds__(256) void k_aw(const float* __restrict__ wsattn,
                                            float* __restrict__ oaw) {
  int idx = blockIdx.x * 256 + threadIdx.x;
  if (idx >= NROW * S_) return;
  int bp = idx / S_, s = idx % S_;
  float acc = 0.f;
#pragma unroll
  for (int h = 0; h < H_; ++h) acc += wsattn[(size_t)(bp * H_ + h) * S_ + s];
  oaw[idx] = acc * 0.125f;
}

// zmat partial: grid (4, 40, 8 k-chunks of 64), 128 thr.  kc==0 carries bias.
__global__ __launch_bounds__(128) void k_zmatp(const float* __restrict__ wsctx,
    const float* __restrict__ Wo, const float* __restrict__ bo,
    float* __restrict__ pz) {
  int c = blockIdx.x * 128 + threadIdx.x;
  int r0 = blockIdx.y * 4;
  int kc = blockIdx.z;
  int d0 = kc * 64;
  float acc[4];
  float bb = (kc == 0) ? bo[c] : 0.f;
#pragma unroll
  for (int rr = 0; rr < 4; ++rr) acc[rr] = bb;
  for (int d = d0; d < d0 + 64; d += 4) {
    float w0 = Wo[(size_t)d * D_ + c],     w1 = Wo[(size_t)(d+1) * D_ + c];
    float w2 = Wo[(size_t)(d+2) * D_ + c], w3 = Wo[(size_t)(d+3) * D_ + c];
#pragma unroll
    for (int rr = 0; rr < 4; ++rr) {
      float4 a = *(const float4*)&wsctx[(size_t)(r0 + rr) * D_ + d];
      acc[rr] = fmaf(a.w, w3, fmaf(a.z, w2, fmaf(a.y, w1, fmaf(a.x, w0, acc[rr]))));
    }
  }
#pragma unroll
  for (int rr = 0; rr < 4; ++rr)
    pz[((size_t)kc * NROW + r0 + rr) * D_ + c] = acc[rr];
}

// FUSED zmat-reduce + LN1: one block per row (160 blocks, 256 thr, 2 elem/thr).
__global__ __launch_bounds__(256) void k_zmatr_ln(const float* __restrict__ pz,
    const float* __restrict__ r, const float* __restrict__ g,
    const float* __restrict__ b, float* __restrict__ oeps,
    float* __restrict__ wsz, float* __restrict__ o,
    uint32_t k4a, uint32_t k4b) {
  __shared__ float red[256];
  int bp = blockIdx.x, tid = threadIdx.x;
  float x0, x1;
  {
    int idx = bp * D_ + tid;
    float s = pz[idx];
#pragma unroll
    for (int kc = 1; kc < 8; ++kc) s += pz[(size_t)kc * (NROW * D_) + idx];
    float eps = SIGMA * jax_normal(k4a, k4b, (uint32_t)idx);
    oeps[idx] = eps;
    float z = s + eps;
    wsz[idx] = z;
    x0 = z + r[idx];
  }
  {
    int idx = bp * D_ + tid + 256;
    float s = pz[idx];
#pragma unroll
    for (int kc = 1; kc < 8; ++kc) s += pz[(size_t)kc * (NROW * D_) + idx];
    float eps = SIGMA * jax_normal(k4a, k4b, (uint32_t)idx);
    oeps[idx] = eps;
    float z = s + eps;
    wsz[idx] = z;
    x1 = z + r[idx];
  }
  red[tid] = x0 + x1; __syncthreads();
  for (int s = 128; s > 0; s >>= 1) { if (tid < s) red[tid] += red[tid + s]; __syncthreads(); }
  float mu = red[0] / (float)D_; __syncthreads();
  float d0 = x0 - mu, d1 = x1 - mu;
  red[tid] = d0 * d0 + d1 * d1; __syncthreads();
  for (int s = 128; s > 0; s >>= 1) { if (tid < s) red[tid] += red[tid + s]; __syncthreads(); }
  float inv = 1.0f / sqrtf(red[0] / (float)D_ + LN_EPS);
  o[bp * D_ + tid] = g[tid] * d0 * inv + b[tid];
  o[bp * D_ + tid + 256] = g[tid + 256] * d1 * inv + b[tid + 256];
}

// ffn1 partial: grid (16, 20, 4 k-chunks of 128), 128 thr.  kc==0 carries b1.
__global__ __launch_bounds__(128) void k_ffn1p(const float* __restrict__ wsout1,
    const float* __restrict__ W1, const float* __restrict__ b1,
    float* __restrict__ pf) {
  int c = blockIdx.x * 128 + threadIdx.x;
  int r0 = blockIdx.y * 8;
  int kc = blockIdx.z;
  int d0 = kc * 128;
  float acc[8];
  float bb = (kc == 0) ? b1[c] : 0.f;
#pragma unroll
  for (int rr = 0; rr < 8; ++rr) acc[rr] = bb;
  for (int d = d0; d < d0 + 128; d += 4) {
    float w0 = W1[(size_t)d * DFF_ + c],     w1 = W1[(size_t)(d+1) * DFF_ + c];
    float w2 = W1[(size_t)(d+2) * DFF_ + c], w3 = W1[(size_t)(d+3) * DFF_ + c];
#pragma unroll
    for (int rr = 0; rr < 8; ++rr) {
      float4 a = *(const float4*)&wsout1[(size_t)(r0 + rr) * D_ + d];
      acc[rr] = fmaf(a.w, w3, fmaf(a.z, w2, fmaf(a.y, w1, fmaf(a.x, w0, acc[rr]))));
    }
  }
#pragma unroll
  for (int rr = 0; rr < 8; ++rr)
    pf[((size_t)kc * NROW + r0 + rr) * DFF_ + c] = acc[rr];
}

// ffn1 reduce + relu
__global__ __launch_bounds__(256) void k_ffn1r(const float* __restrict__ pf,
    float* __restrict__ wsffn) {
  int idx = blockIdx.x * 256 + threadIdx.x;
  if (idx >= NROW * DFF_) return;
  float s = pf[idx];
#pragma unroll
  for (int kc = 1; kc < 4; ++kc) s += pf[(size_t)kc * (NROW * DFF_) + idx];
  wsffn[idx] = fmaxf(s, 0.f);
}

// ffn2 partial: grid (4, 40, 16 k-chunks of 128), 128 thr.
__global__ __launch_bounds__(128) void k_ffn2p(const float* __restrict__ wsffn,
    const float* __restrict__ W2, float* __restrict__ p2) {
  int c = blockIdx.x * 128 + threadIdx.x;
  int r0 = blockIdx.y * 4;
  int kc = blockIdx.z;
  int d0 = kc * 128;
  float acc[4];
#pragma unroll
  for (int rr = 0; rr < 4; ++rr) acc[rr] = 0.f;
  for (int d = d0; d < d0 + 128; d += 4) {
    float w0 = W2[(size_t)d * D_ + c],     w1 = W2[(size_t)(d+1) * D_ + c];
    float w2 = W2[(size_t)(d+2) * D_ + c], w3 = W2[(size_t)(d+3) * D_ + c];
#pragma unroll
    for (int rr = 0; rr < 4; ++rr) {
      float4 a = *(const float4*)&wsffn[(size_t)(r0 + rr) * DFF_ + d];
      acc[rr] = fmaf(a.w, w3, fmaf(a.z, w2, fmaf(a.y, w1, fmaf(a.x, w0, acc[rr]))));
    }
  }
#pragma unroll
  for (int rr = 0; rr < 4; ++rr)
    p2[((size_t)kc * NROW + r0 + rr) * D_ + c] = acc[rr];
}

// FUSED ffn2-reduce + LN3: writes out3 directly.
__global__ __launch_bounds__(256) void k_ffn2r_ln(const float* __restrict__ p2,
    const float* __restrict__ b2, const float* __restrict__ wsout1,
    const float* __restrict__ g, const float* __restrict__ b,
    float* __restrict__ o) {
  __shared__ float red[256];
  int bp = blockIdx.x, tid = threadIdx.x;
  float x0, x1;
  {
    int idx = bp * D_ + tid;
    float s = p2[idx];
#pragma unroll
    for (int kc = 1; kc < 16; ++kc) s += p2[(size_t)kc * (NROW * D_) + idx];
    x0 = s + b2[tid] + wsout1[idx];
  }
  {
    int idx = bp * D_ + tid + 256;
    float s = p2[idx];
#pragma unroll
    for (int kc = 1; kc < 16; ++kc) s += p2[(size_t)kc * (NROW * D_) + idx];
    x1 = s + b2[tid + 256] + wsout1[idx];
  }
  red[tid] = x0 + x1; __syncthreads();
  for (int s = 128; s > 0; s >>= 1) { if (tid < s) red[tid] += red[tid + s]; __syncthreads(); }
  float mu = red[0] / (float)D_; __syncthreads();
  float d0 = x0 - mu, d1 = x1 - mu;
  red[tid] = d0 * d0 + d1 * d1; __syncthreads();
  for (int s = 128; s > 0; s >>= 1) { if (tid < s) red[tid] += red[tid + s]; __syncthreads(); }
  float inv = 1.0f / sqrtf(red[0] / (float)D_ + LN_EPS);
  o[bp * D_ + tid] = g[tid] * d0 * inv + b[tid];
  o[bp * D_ + tid + 256] = g[tid + 256] * d1 * inv + b[tid + 256];
}

// predictions = out3 @ Wout + bout  (160 x 512 x 32000)
// BEST-MEASURED VARIANT (R3, 111us): 80 rows x 64 cols per block, 256 thr,
// per-thread 5 rows x 4 cols (20 acc), grid (500, 2), single-buffer LDS
// A[80][68], JIT W loads, plain stores.  Nine structural variants (deep
// prefetch, team-split, no-LDS, dbuf-LDS, atomics, traffic-halved shape)
// all measured worse: invariant VALUBusy*dur ~ 43-48us with duty ~15%
// regardless of shape; this config maximizes wave count at that duty.
// Accumulation order: bias head, d ascending -> matches k-split semantics.
__global__ __launch_bounds__(256, 4) void k_preds(const float* __restrict__ A,
    const float* __restrict__ Wout, const float* __restrict__ bout,
    float* __restrict__ wspred) {
  __shared__ float sA[80][68];   // 21.76 KB
  int tid = threadIdx.x;
  int cb = blockIdx.x, rh = blockIdx.y;
  int cg = tid & 15, rg = tid >> 4;
  int c = cb * 64 + cg * 4;
  float4 acc[5];
  {
    float4 b0 = *(const float4*)&bout[c];
#pragma unroll
    for (int i = 0; i < 5; ++i) acc[i] = b0;
  }
  const float* Ab = A + (size_t)rh * 80 * D_;
  for (int d0 = 0; d0 < D_; d0 += 64) {
    if (d0) __syncthreads();       // previous chunk's reads done
    // stage A[rh*80 : +80][d0:d0+64]: 1280 float4, 5 per thread, coalesced
#pragma unroll
    for (int k = 0; k < 5; ++k) {
      int idx = tid + k * 256;
      int row = idx >> 4, c4 = idx & 15;
      *(float4*)&sA[row][c4 * 4] =
          *(const float4*)&Ab[(size_t)row * D_ + d0 + c4 * 4];
    }
    __syncthreads();
#pragma unroll 2
    for (int dd = 0; dd < 64; dd += 4) {
      size_t wb = (size_t)(d0 + dd) * VOC_ + c;
      float4 w0 = *(const float4*)&Wout[wb];
      float4 w1 = *(const float4*)&Wout[wb + VOC_];
      float4 w2 = *(const float4*)&Wout[wb + 2 * (size_t)VOC_];
      float4 w3 = *(const float4*)&Wout[wb + 3 * (size_t)VOC_];
#pragma unroll
      for (int i = 0; i < 5; ++i) {
        float4 a = *(const float4*)&sA[rg * 5 + i][dd];
        acc[i].x = fmaf(a.x, w0.x, acc[i].x); acc[i].y = fmaf(a.x, w0.y, acc[i].y);
        acc[i].z = fmaf(a.x, w0.z, acc[i].z); acc[i].w = fmaf(a.x, w0.w, acc[i].w);
        acc[i].x = fmaf(a.y, w1.x, acc[i].x); acc[i].y = fmaf(a.y, w1.y, acc[i].y);
        acc[i].z = fmaf(a.y, w1.z, acc[i].z); acc[i].w = fmaf(a.y, w1.w, acc[i].w);
        acc[i].x = fmaf(a.z, w2.x, acc[i].x); acc[i].y = fmaf(a.z, w2.y, acc[i].y);
        acc[i].z = fmaf(a.z, w2.z, acc[i].z); acc[i].w = fmaf(a.z, w2.w, acc[i].w);
        acc[i].x = fmaf(a.w, w3.x, acc[i].x); acc[i].y = fmaf(a.w, w3.y, acc[i].y);
        acc[i].z = fmaf(a.w, w3.z, acc[i].z); acc[i].w = fmaf(a.w, w3.w, acc[i].w);
      }
    }
  }
#pragma unroll
  for (int i = 0; i < 5; ++i) {
    size_t o = (size_t)(rh * 80 + rg * 5 + i) * VOC_ + c;
    *(float4*)&wspred[o] = acc[i];
  }
}

// per-row softmax stats over VOC; w[b,p] = probs at x[b]
__global__ __launch_bounds__(256) void k_stats(const float* __restrict__ wspred,
    const int* __restrict__ x, float* __restrict__ ow) {
  __shared__ float red[256];
  int bp = blockIdx.x, tid = threadIdx.x;
  const float* row = wspred + (size_t)bp * VOC_;
  const float4* row4 = (const float4*)row;
  float m = -INFINITY;
  for (int i = tid; i < VOC_ / 4; i += 256) {
    float4 v = row4[i];
    m = fmaxf(m, fmaxf(fmaxf(v.x, v.y), fmaxf(v.z, v.w)));
  }
  red[tid] = m; __syncthreads();
  for (int s = 128; s > 0; s >>= 1) { if (tid < s) red[tid] = fmaxf(red[tid], red[tid + s]); __syncthreads(); }
  m = red[0]; __syncthreads();
  float sum = 0.f;
  for (int i = tid; i < VOC_ / 4; i += 256) {
    float4 v = row4[i];
    sum += expf(v.x - m) + expf(v.y - m) + expf(v.z - m) + expf(v.w - m);
  }
  red[tid] = sum; __syncthreads();
  for (int s = 128; s > 0; s >>= 1) { if (tid < s) red[tid] += red[tid + s]; __syncthreads(); }
  if (tid == 0) {
    int b = bp / P_;
    ow[bp] = expf(row[x[b]] - m) / red[0];
  }
}

// i_t via gumbel-argmax; argmax_w per batch
__global__ __launch_bounds__(256) void k_it(const float* __restrict__ ow,
    int* __restrict__ wsit, int* __restrict__ wsamw,
    uint32_t k5a, uint32_t k5b) {
  int tid = threadIdx.x;
  if (tid < NROW) {
    int b = tid / P_;
    float best = -INFINITY; int bi = 0;
#pragma unroll
    for (int i = 0; i < P_; ++i) {
      float g = jax_gumbel(k5a, k5b, (uint32_t)(tid * P_ + i));
      float v = g + ow[b * P_ + i];
      if (v > best) { best = v; bi = i; }
    }
    wsit[tid] = bi;
  }
  if (tid < B_) {
    float best = -INFINITY; int bi = 0;
#pragma unroll
    for (int p = 0; p < P_; ++p) {
      float v = ow[tid * P_ + p];
      if (v > best) { best = v; bi = p; }
    }
    wsamw[tid] = bi;
  }
}

// MERGED tail: blocks [0,2000) = avgmax; blocks [2000,2320) = zsel+I_new.
__global__ __launch_bounds__(256) void k_tail(const float* __restrict__ wspred,
    const float* __restrict__ ow, const int* __restrict__ wsamw,
    const float* __restrict__ wsz, const int* __restrict__ wsit,
    const int* __restrict__ I, const int* __restrict__ tptr,
    float* __restrict__ oavg, float* __restrict__ omax,
    float* __restrict__ oz, float* __restrict__ oI) {
  int bid = blockIdx.x, tid = threadIdx.x;
  if (bid < 2000) {
    int idx = bid * 256 + tid;
    if (idx >= B_ * VOC_) return;
    int b = idx / VOC_, c = idx % VOC_;
    float acc = 0.f;
#pragma unroll
    for (int p = 0; p < P_; ++p)
      acc = fmaf(wspred[(size_t)(b * P_ + p) * VOC_ + c], ow[b * P_ + p], acc);
    oavg[idx] = acc;
    omax[idx] = wspred[(size_t)(b * P_ + wsamw[b]) * VOC_ + c];
  } else {
    int idx = (bid - 2000) * 256 + tid;
    if (idx < NROW * D_) {
      int bp = idx / D_, d = idx % D_;
      int b = bp / P_;
      oz[idx] = wsz[(size_t)(b * P_ + wsit[bp]) * D_ + d];
    }
    if (idx < NROW * S_) {
      int bp = idx / S_, s = idx % S_;
      int ts = min(max(*tptr, 0), S_ - 1);
      oI[idx] = (s == ts) ? (float)wsit[bp] : (float)I[idx];
    }
  }
}

// ---------------- Host launch ----------------
static void derive_keys(uint32_t keys[5][2]) {
  for (int i = 0; i < 5; ++i) {
    U2 o = tf2x32(0u, 42u, 0u, (uint32_t)i);
    keys[i][0] = o.x; keys[i][1] = o.y;
  }
}

extern "C" void kernel_launch(void* const* d_in, const int* in_sizes, int n_in,
                              void* d_out, int out_size, void* d_ws, size_t ws_size,
                              hipStream_t stream) {
  const float* r   = (const float*)d_in[0];
  const int*   x   = (const int*)d_in[1];
  const float* K   = (const float*)d_in[2];
  const float* V   = (const float*)d_in[3];
  const int*   I   = (const int*)d_in[5];
  const int*   tp  = (const int*)d_in[6];
  const float* Wq  = (const float*)d_in[7];
  const float* bq  = (const float*)d_in[8];
  const float* Wk  = (const float*)d_in[9];
  const float* bk  = (const float*)d_in[10];
  const float* Wv  = (const float*)d_in[11];
  const float* bv  = (const float*)d_in[12];
  const float* Wo  = (const float*)d_in[13];
  const float* bo  = (const float*)d_in[14];
  const float* W1  = (const float*)d_in[15];
  const float* b1  = (const float*)d_in[16];
  const float* W2  = (const float*)d_in[17];
  const float* b2  = (const float*)d_in[18];
  const float* g1  = (const float*)d_in[19];
  const float* be1 = (const float*)d_in[20];
  const float* g3  = (const float*)d_in[21];
  const float* be3 = (const float*)d_in[22];
  const float* Wout = (const float*)d_in[23];
  const float* bout = (const float*)d_in[24];

  float* out = (float*)d_out;
  const size_t O_OUT3 = 0;
  const size_t O_Z    = 81920;
  const size_t O_AVG  = 163840;
  const size_t O_MAX  = 675840;
  const size_t O_EPS  = 1187840;
  const size_t O_AW   = 1269760;
  const size_t O_K    = 1290240;
  const size_t O_V    = 11776000;
  const size_t O_W    = 22261760;
  const size_t O_I    = 22261920;

  float* ws = (float*)d_ws;
  const size_t W_Q    = 0;
  const size_t W_CTX  = 81920;
  const size_t W_Z    = 163840;
  const size_t W_OUT1 = 245760;
  const size_t W_ATT  = 327680;   // 163840
  const size_t W_FFN  = 491520;   // 327680
  const size_t W_PRED = 819200;   // 5120000 -- also reused as K-split scratch
  const size_t W_IT   = 5939200;
  const size_t W_AMW  = 5939360;

  uint32_t kk[5][2];
  derive_keys(kk);

  float* oK = out + O_K;
  float* oV = out + O_V;
  float* sc = ws + W_PRED;        // K-split partial scratch (dead before k_preds)

  k_gather<<<10240, 256, 0, stream>>>(K, V, I, oK, oV);
  k_qkvp<<<dim3(4, 40, 8), 128, 0, stream>>>(r, Wq, bq, Wk, bk, Wv, bv,
                                             sc, sc + 655360, sc + 1310720);
  k_qkvr<<<320, 256, 0, stream>>>(sc, sc + 655360, sc + 1310720, tp,
                                  ws + W_Q, oK, oV,
                                  kk[0][0], kk[0][1], kk[1][0], kk[1][1],
                                  kk[2][0], kk[2][1]);
  k_attn<<<NROW * H_, 128, 0, stream>>>(ws + W_Q, oK, oV, ws + W_CTX, ws + W_ATT);
  k_aw<<<(NROW * S_ + 255) / 256, 256, 0, stream>>>(ws + W_ATT, out + O_AW);
  k_zmatp<<<dim3(4, 40, 8), 128, 0, stream>>>(ws + W_CTX, Wo, bo, sc);
  k_zmatr_ln<<<NROW, 256, 0, stream>>>(sc, r, g1, be1, out + O_EPS, ws + W_Z,
                                       ws + W_OUT1, kk[3][0], kk[3][1]);
  k_ffn1p<<<dim3(16, 20, 4), 128, 0, stream>>>(ws + W_OUT1, W1, b1, sc);
  k_ffn1r<<<1280, 256, 0, stream>>>(sc, ws + W_FFN);
  k_ffn2p<<<dim3(4, 40, 16), 128, 0, stream>>>(ws + W_FFN, W2, sc);
  k_ffn2r_ln<<<NROW, 256, 0, stream>>>(sc, b2, ws + W_OUT1, g3, be3, out + O_OUT3);
  k_preds<<<dim3(500, 2), 256, 0, stream>>>(out + O_OUT3, Wout, bout, ws + W_PRED);
  k_stats<<<NROW, 256, 0, stream>>>(ws + W_PRED, x, out + O_W);
  k_it<<<1, 256, 0, stream>>>(out + O_W, (int*)(ws + W_IT), (int*)(ws + W_AMW),
                              kk[4][0], kk[4][1]);
  k_tail<<<2320, 256, 0, stream>>>(ws + W_PRED, out + O_W,
                                   (const int*)(ws + W_AMW), ws + W_Z,
                                   (const int*)(ws + W_IT), I, tp,
                                   out + O_AVG, out + O_MAX,
                                   out + O_Z, out + O_I);
}

// Round 11
// 427.017 us; speedup vs baseline: 1.6801x; 1.0270x over previous
//
#include <hip/hip_runtime.h>
#include <cstdint>
#include <cstddef>

#define B_    16
#define P_    10
#define S_    128
#define D_    512
#define H_    8
#define DH_   64
#define DFF_  2048
#define VOC_  32000
#define NROW  160   // B*P
#define SIGMA 0.05f
#define LN_EPS 1e-6f

// ---------------- Threefry2x32 (bit-exact vs JAX) ----------------
struct U2 { uint32_t x, y; };

__host__ __device__ __forceinline__ U2 tf2x32(uint32_t k0, uint32_t k1,
                                              uint32_t x0, uint32_t x1) {
  uint32_t ks[3] = {k0, k1, k0 ^ k1 ^ 0x1BD11BDAu};
  x0 += ks[0]; x1 += ks[1];
  const int R0[4] = {13, 15, 26, 6};
  const int R1[4] = {17, 29, 16, 24};
#pragma unroll
  for (int i = 0; i < 5; ++i) {
    const int* r = (i & 1) ? R1 : R0;
#pragma unroll
    for (int j = 0; j < 4; ++j) {
      x0 += x1;
      x1 = (x1 << r[j]) | (x1 >> (32 - r[j]));
      x1 ^= x0;
    }
    x0 += ks[(i + 1) % 3];
    x1 += ks[(i + 2) % 3] + (uint32_t)(i + 1);
  }
  return {x0, x1};
}

__device__ __forceinline__ uint32_t jax_bits32(uint32_t k0, uint32_t k1, uint32_t j) {
  U2 o = tf2x32(k0, k1, 0u, j);
  return o.x ^ o.y;
}

__device__ __forceinline__ float erfinv32(float x) {
  float w = -log1pf(-x * x);
  float p;
  if (w < 5.0f) {
    w = w - 2.5f;
    p = 2.81022636e-08f;
    p = fmaf(p, w, 3.43273939e-07f);
    p = fmaf(p, w, -3.5233877e-06f);
    p = fmaf(p, w, -4.39150654e-06f);
    p = fmaf(p, w, 0.00021858087f);
    p = fmaf(p, w, -0.00125372503f);
    p = fmaf(p, w, -0.00417768164f);
    p = fmaf(p, w, 0.246640727f);
    p = fmaf(p, w, 1.50140941f);
  } else {
    w = sqrtf(w) - 3.0f;
    p = -0.000200214257f;
    p = fmaf(p, w, 0.000100950558f);
    p = fmaf(p, w, 0.00134934322f);
    p = fmaf(p, w, -0.00367342844f);
    p = fmaf(p, w, 0.00573950773f);
    p = fmaf(p, w, -0.0076224613f);
    p = fmaf(p, w, 0.00943887047f);
    p = fmaf(p, w, 1.00167406f);
    p = fmaf(p, w, 2.83297682f);
  }
  return p * x;
}

__device__ __forceinline__ float jax_normal(uint32_t k0, uint32_t k1, uint32_t j) {
  uint32_t b = jax_bits32(k0, k1, j);
  float u01 = __uint_as_float((b >> 9) | 0x3F800000u) - 1.0f;
  const float lo = -0.99999994f;
  float u = fmaxf(lo, fmaf(u01, 2.0f, lo));
  return 1.41421356f * erfinv32(u);
}

__device__ __forceinline__ float jax_gumbel(uint32_t k0, uint32_t k1, uint32_t j) {
  uint32_t b = jax_bits32(k0, k1, j);
  float u01 = __uint_as_float((b >> 9) | 0x3F800000u) - 1.0f;
  const float tiny = 1.17549435e-38f;
  float u = fmaxf(tiny, u01 + tiny);
  return -logf(-logf(u));
}

// ---------------- Kernels ----------------

// MERGED gather + qkv-partial.  The two are fully independent (disjoint
// in/out; both consumed only by k_qkvr next launch) -> one launch removes a
// graph gap AND overlaps the L2-bound qkv GEMM under the HBM-bound 336 MB
// gather stream.  qkvp blocks FIRST (bid < 1280) so they start immediately.
__global__ __launch_bounds__(256) void k_gq(const float* __restrict__ K,
    const float* __restrict__ V, const int* __restrict__ I,
    float* __restrict__ oK, float* __restrict__ oV,
    const float* __restrict__ r,
    const float* __restrict__ Wq, const float* __restrict__ bq,
    const float* __restrict__ Wk, const float* __restrict__ bk,
    const float* __restrict__ Wv, const float* __restrict__ bv,
    float* __restrict__ pq, float* __restrict__ pk, float* __restrict__ pv) {
  int bid = blockIdx.x;
  int tid = threadIdx.x;
  if (bid < 1280) {
    // ---- qkv partial: virtual grid (4 colchunks, 40 rowtiles, 8 kchunks) ----
    if (tid >= 128) return;
    int cchunk = bid & 3;
    int rowt = (bid >> 2) % 40;
    int kc = (bid >> 2) / 40;
    int c = cchunk * 128 + tid;
    int r0 = rowt * 4;
    int d0 = kc * 64;
    float aq[4], ak[4], av[4];
    float bbq = (kc == 0) ? bq[c] : 0.f;
    float bbk = (kc == 0) ? bk[c] : 0.f;
    float bbv = (kc == 0) ? bv[c] : 0.f;
#pragma unroll
    for (int rr = 0; rr < 4; ++rr) { aq[rr] = bbq; ak[rr] = bbk; av[rr] = bbv; }
    for (int d = d0; d < d0 + 64; d += 4) {
      float wq0 = Wq[(size_t)d * D_ + c],      wq1 = Wq[(size_t)(d+1) * D_ + c];
      float wq2 = Wq[(size_t)(d+2) * D_ + c],  wq3 = Wq[(size_t)(d+3) * D_ + c];
      float wk0 = Wk[(size_t)d * D_ + c],      wk1 = Wk[(size_t)(d+1) * D_ + c];
      float wk2 = Wk[(size_t)(d+2) * D_ + c],  wk3 = Wk[(size_t)(d+3) * D_ + c];
      float wv0 = Wv[(size_t)d * D_ + c],      wv1 = Wv[(size_t)(d+1) * D_ + c];
      float wv2 = Wv[(size_t)(d+2) * D_ + c],  wv3 = Wv[(size_t)(d+3) * D_ + c];
#pragma unroll
      for (int rr = 0; rr < 4; ++rr) {
        float4 a = *(const float4*)&r[(size_t)(r0 + rr) * D_ + d];
        aq[rr] = fmaf(a.w, wq3, fmaf(a.z, wq2, fmaf(a.y, wq1, fmaf(a.x, wq0, aq[rr]))));
        ak[rr] = fmaf(a.w, wk3, fmaf(a.z, wk2, fmaf(a.y, wk1, fmaf(a.x, wk0, ak[rr]))));
        av[rr] = fmaf(a.w, wv3, fmaf(a.z, wv2, fmaf(a.y, wv1, fmaf(a.x, wv0, av[rr]))));
      }
    }
#pragma unroll
    for (int rr = 0; rr < 4; ++rr) {
      size_t o = ((size_t)kc * NROW + r0 + rr) * D_ + c;
      pq[o] = aq[rr]; pk[o] = ak[rr]; pv[o] = av[rr];
    }
  } else {
    // ---- gather: float4 copy with particle indirection ----
    size_t idx = (size_t)(bid - 1280) * 256 + tid;
    const size_t total = (size_t)NROW * S_ * (D_ / 4);
    if (idx >= total) return;
    int d4 = (int)(idx % (D_ / 4));
    size_t row = idx / (D_ / 4);                               // bp*S + s
    int s = (int)(row % S_);
    int bp = (int)(row / S_);
    int b = bp / P_;
    int iv = I[row];
    size_t src = ((size_t)(b * P_ + iv) * S_ + s) * (D_ / 4) + d4;
    ((float4*)oK)[idx] = ((const float4*)K)[src];
    ((float4*)oV)[idx] = ((const float4*)V)[src];
  }
}

// qkv reduce: sum 8 partials (ascending), add noise, scatter K/V at ts.
__global__ __launch_bounds__(256) void k_qkvr(const float* __restrict__ pq,
    const float* __restrict__ pk, const float* __restrict__ pv,
    const int* __restrict__ tptr, float* __restrict__ wsq,
    float* __restrict__ oK, float* __restrict__ oV,
    uint32_t k1a, uint32_t k1b, uint32_t k2a, uint32_t k2b,
    uint32_t k3a, uint32_t k3b) {
  int idx = blockIdx.x * 256 + threadIdx.x;
  if (idx >= NROW * D_) return;
  float q = pq[idx], k = pk[idx], v = pv[idx];
#pragma unroll
  for (int kc = 1; kc < 8; ++kc) {
    size_t o = (size_t)kc * (NROW * D_) + idx;
    q += pq[o]; k += pk[o]; v += pv[o];
  }
  int bp = idx / D_, c = idx % D_;
  int ts = min(max(*tptr, 0), S_ - 1);
  uint32_t j = (uint32_t)idx;
  wsq[idx] = q + SIGMA * jax_normal(k1a, k1b, j);
  oK[((size_t)bp * S_ + ts) * D_ + c] = k + SIGMA * jax_normal(k2a, k2b, j);
  oV[((size_t)bp * S_ + ts) * D_ + c] = v + SIGMA * jax_normal(k3a, k3b, j);
}

// attention: one block per (bp, h); 128 threads (one per s).
// PV uses all 128 lanes: two s-halves, LDS combine.
__global__ __launch_bounds__(128) void k_attn(const float* __restrict__ wsq,
    const float* __restrict__ oK, const float* __restrict__ oV,
    float* __restrict__ wsctx, float* __restrict__ wsattn) {
  __shared__ float s_q[DH_];
  __shared__ float s_attn[S_];
  __shared__ float red[S_];
  int bp = blockIdx.x >> 3, h = blockIdx.x & 7, tid = threadIdx.x;
  if (tid < DH_) s_q[tid] = wsq[bp * D_ + h * DH_ + tid];
  __syncthreads();
  const float4* krow = (const float4*)(oK + ((size_t)bp * S_ + tid) * D_ + h * DH_);
  const float4* q4 = (const float4*)s_q;
  float sc = 0.f;
#pragma unroll
  for (int d = 0; d < DH_ / 4; ++d) {
    float4 kv = krow[d], qv = q4[d];
    sc += qv.x * kv.x + qv.y * kv.y + qv.z * kv.z + qv.w * kv.w;
  }
  sc *= 0.125f;  // 1/sqrt(64)
  red[tid] = sc; __syncthreads();
  for (int s = 64; s > 0; s >>= 1) {
    if (tid < s) red[tid] = fmaxf(red[tid], red[tid + s]);
    __syncthreads();
  }
  float m = red[0]; __syncthreads();
  float e = expf(sc - m);
  red[tid] = e; __syncthreads();
  for (int s = 64; s > 0; s >>= 1) {
    if (tid < s) red[tid] += red[tid + s];
    __syncthreads();
  }
  float a = e / red[0];
  s_attn[tid] = a;
  wsattn[(size_t)blockIdx.x * S_ + tid] = a;
  __syncthreads();
  {
    int dd = tid & 63, sh = tid >> 6;   // sh in {0,1}: s-half
    const float* vb = oV + ((size_t)bp * S_ + sh * 64) * D_ + h * DH_ + dd;
    float acc = 0.f;
#pragma unroll 4
    for (int s = 0; s < 64; ++s) acc = fmaf(s_attn[sh * 64 + s], vb[(size_t)s * D_], acc);
    red[tid] = acc; __syncthreads();
    if (tid < DH_) wsctx[bp * D_ + h * DH_ + tid] = red[tid] + red[tid + 64];
  }
}

// MERGED zmat-partial + attn-weights-mean.  Both depend only on k_attn and
// have disjoint outputs -> one launch.  zmatp blocks first (bid < 1280,
// virtual grid (4,40,8), 128 active lanes); aw blocks after (80 x 256 thr).
__global__ __launch_bounds__(256) void k_zaw(const float* __restrict__ wsctx,
    const float* __restrict__ Wo, const float* __restrict__ bo,
    float* __restrict__ pz,
    const float* __restrict__ wsattn, float* __restrict__ oaw) {
  int bid = blockIdx.x;
  int tid = threadIdx.x;
  if (bid < 1280) {
    if (tid >= 128) return;
    int cchunk = bid & 3;
    int rowt = (bid >> 2) % 40;
    int kc = (bid >> 2) / 40;
    int c = cchunk * 128 + tid;
    int r0 = rowt * 4;
    int d0 = kc * 64;
    float acc[4];
    float bb = (kc == 0) ? bo[c] : 0.f;
#pragma unroll
    for (int rr = 0; rr < 4; ++rr) acc[rr] = bb;
    for (int d = d0; d < d0 + 64; d += 4) {
      float w0 = Wo[(size_t)d * D_ + c],     w1 = Wo[(size_t)(d+1) * D_ + c];
      float w2 = Wo[(size_t)(d+2) * D_ + c], w3 = Wo[(size_t)(d+3) * D_ + c];
#pragma unroll
      for (int rr = 0; rr < 4; ++rr) {
        float4 a = *(const float4*)&wsctx[(size_t)(r0 + rr) * D_ + d];
        acc[rr] = fmaf(a.w, w3, fmaf(a.z, w2, fmaf(a.y, w1, fmaf(a.x, w0, acc[rr]))));
      }
    }
#pragma unroll
    for (int rr = 0; rr < 4; ++rr)
      pz[((size_t)kc * NROW + r0 + rr) * D_ + c] = acc[rr];
  } else {
    int idx = (bid - 1280) * 256 + tid;
    if (idx >= NROW * S_) return;
    int bp = idx / S_, s = idx % S_;
    float acc = 0.f;
#pragma unroll
    for (int h = 0; h < H_; ++h) acc += wsattn[(size_t)(bp * H_ + h) * S_ + s];
    oaw[idx] = acc * 0.125f;
  }
}

// FUSED zmat-reduce + LN1: one block per row (160 blocks, 256 thr, 2 elem/thr).
__global__ __launch_bounds__(256) void k_zmatr_ln(const float* __restrict__ pz,
    const float* __restrict__ r, const float* __restrict__ g,
    const float* __restrict__ b, float* __restrict__ oeps,
    float* __restrict__ wsz, float* __restrict__ o,
    uint32_t k4a, uint32_t k4b) {
  __shared__ float red[256];
  int bp = blockIdx.x, tid = threadIdx.x;
  float x0, x1;
  {
    int idx = bp * D_ + tid;
    float s = pz[idx];
#pragma unroll
    for (int kc = 1; kc < 8; ++kc) s += pz[(size_t)kc * (NROW * D_) + idx];
    float eps = SIGMA * jax_normal(k4a, k4b, (uint32_t)idx);
    oeps[idx] = eps;
    float z = s + eps;
    wsz[idx] = z;
    x0 = z + r[idx];
  }
  {
    int idx = bp * D_ + tid + 256;
    float s = pz[idx];
#pragma unroll
    for (int kc = 1; kc < 8; ++kc) s += pz[(size_t)kc * (NROW * D_) + idx];
    float eps = SIGMA * jax_normal(k4a, k4b, (uint32_t)idx);
    oeps[idx] = eps;
    float z = s + eps;
    wsz[idx] = z;
    x1 = z + r[idx];
  }
  red[tid] = x0 + x1; __syncthreads();
  for (int s = 128; s > 0; s >>= 1) { if (tid < s) red[tid] += red[tid + s]; __syncthreads(); }
  float mu = red[0] / (float)D_; __syncthreads();
  float d0 = x0 - mu, d1 = x1 - mu;
  red[tid] = d0 * d0 + d1 * d1; __syncthreads();
  for (int s = 128; s > 0; s >>= 1) { if (tid < s) red[tid] += red[tid + s]; __syncthreads(); }
  float inv = 1.0f / sqrtf(red[0] / (float)D_ + LN_EPS);
  o[bp * D_ + tid] = g[tid] * d0 * inv + b[tid];
  o[bp * D_ + tid + 256] = g[tid + 256] * d1 * inv + b[tid + 256];
}

// ffn1 partial: grid (16, 20, 4 k-chunks of 128), 128 thr.  kc==0 carries b1.
__global__ __launch_bounds__(128) void k_ffn1p(const float* __restrict__ wsout1,
    const float* __restrict__ W1, const float* __restrict__ b1,
    float* __restrict__ pf) {
  int c = blockIdx.x * 128 + threadIdx.x;
  int r0 = blockIdx.y * 8;
  int kc = blockIdx.z;
  int d0 = kc * 128;
  float acc[8];
  float bb = (kc == 0) ? b1[c] : 0.f;
#pragma unroll
  for (int rr = 0; rr < 8; ++rr) acc[rr] = bb;
  for (int d = d0; d < d0 + 128; d += 4) {
    float w0 = W1[(size_t)d * DFF_ + c],     w1 = W1[(size_t)(d+1) * DFF_ + c];
    float w2 = W1[(size_t)(d+2) * DFF_ + c], w3 = W1[(size_t)(d+3) * DFF_ + c];
#pragma unroll
    for (int rr = 0; rr < 8; ++rr) {
      float4 a = *(const float4*)&wsout1[(size_t)(r0 + rr) * D_ + d];
      acc[rr] = fmaf(a.w, w3, fmaf(a.z, w2, fmaf(a.y, w1, fmaf(a.x, w0, acc[rr]))));
    }
  }
#pragma unroll
  for (int rr = 0; rr < 8; ++rr)
    pf[((size_t)kc * NROW + r0 + rr) * DFF_ + c] = acc[rr];
}

// ffn1 reduce + relu
__global__ __launch_bounds__(256) void k_ffn1r(const float* __restrict__ pf,
    float* __restrict__ wsffn) {
  int idx = blockIdx.x * 256 + threadIdx.x;
  if (idx >= NROW * DFF_) return;
  float s = pf[idx];
#pragma unroll
  for (int kc = 1; kc < 4; ++kc) s += pf[(size_t)kc * (NROW * DFF_) + idx];
  wsffn[idx] = fmaxf(s, 0.f);
}

// ffn2 partial: grid (4, 40, 16 k-chunks of 128), 128 thr.
__global__ __launch_bounds__(128) void k_ffn2p(const float* __restrict__ wsffn,
    const float* __restrict__ W2, float* __restrict__ p2) {
  int c = blockIdx.x * 128 + threadIdx.x;
  int r0 = blockIdx.y * 4;
  int kc = blockIdx.z;
  int d0 = kc * 128;
  float acc[4];
#pragma unroll
  for (int rr = 0; rr < 4; ++rr) acc[rr] = 0.f;
  for (int d = d0; d < d0 + 128; d += 4) {
    float w0 = W2[(size_t)d * D_ + c],     w1 = W2[(size_t)(d+1) * D_ + c];
    float w2 = W2[(size_t)(d+2) * D_ + c], w3 = W2[(size_t)(d+3) * D_ + c];
#pragma unroll
    for (int rr = 0; rr < 4; ++rr) {
      float4 a = *(const float4*)&wsffn[(size_t)(r0 + rr) * DFF_ + d];
      acc[rr] = fmaf(a.w, w3, fmaf(a.z, w2, fmaf(a.y, w1, fmaf(a.x, w0, acc[rr]))));
    }
  }
#pragma unroll
  for (int rr = 0; rr < 4; ++rr)
    p2[((size_t)kc * NROW + r0 + rr) * D_ + c] = acc[rr];
}

// FUSED ffn2-reduce + LN3: writes out3 directly.
__global__ __launch_bounds__(256) void k_ffn2r_ln(const float* __restrict__ p2,
    const float* __restrict__ b2, const float* __restrict__ wsout1,
    const float* __restrict__ g, const float* __restrict__ b,
    float* __restrict__ o) {
  __shared__ float red[256];
  int bp = blockIdx.x, tid = threadIdx.x;
  float x0, x1;
  {
    int idx = bp * D_ + tid;
    float s = p2[idx];
#pragma unroll
    for (int kc = 1; kc < 16; ++kc) s += p2[(size_t)kc * (NROW * D_) + idx];
    x0 = s + b2[tid] + wsout1[idx];
  }
  {
    int idx = bp * D_ + tid + 256;
    float s = p2[idx];
#pragma unroll
    for (int kc = 1; kc < 16; ++kc) s += p2[(size_t)kc * (NROW * D_) + idx];
    x1 = s + b2[tid + 256] + wsout1[idx];
  }
  red[tid] = x0 + x1; __syncthreads();
  for (int s = 128; s > 0; s >>= 1) { if (tid < s) red[tid] += red[tid + s]; __syncthreads(); }
  float mu = red[0] / (float)D_; __syncthreads();
  float d0 = x0 - mu, d1 = x1 - mu;
  red[tid] = d0 * d0 + d1 * d1; __syncthreads();
  for (int s = 128; s > 0; s >>= 1) { if (tid < s) red[tid] += red[tid + s]; __syncthreads(); }
  float inv = 1.0f / sqrtf(red[0] / (float)D_ + LN_EPS);
  o[bp * D_ + tid] = g[tid] * d0 * inv + b[tid];
  o[bp * D_ + tid + 256] = g[tid + 256] * d1 * inv + b[tid + 256];
}

// predictions = out3 @ Wout + bout  (160 x 512 x 32000)
// BEST-MEASURED VARIANT (R3/R9, 111us): 80 rows x 64 cols per block, 256
// thr, per-thread 5 rows x 4 cols (20 acc), grid (500, 2), single-buffer
// LDS A[80][68], JIT W loads, plain stores.  Nine structural variants all
// measured worse; VALUBusy*dur ~ 45us invariant with duty ~15% regardless
// of shape; this config maximizes wave count at that duty.  DO NOT TOUCH.
__global__ __launch_bounds__(256, 4) void k_preds(const float* __restrict__ A,
    const float* __restrict__ Wout, const float* __restrict__ bout,
    float* __restrict__ wspred) {
  __shared__ float sA[80][68];   // 21.76 KB
  int tid = threadIdx.x;
  int cb = blockIdx.x, rh = blockIdx.y;
  int cg = tid & 15, rg = tid >> 4;
  int c = cb * 64 + cg * 4;
  float4 acc[5];
  {
    float4 b0 = *(const float4*)&bout[c];
#pragma unroll
    for (int i = 0; i < 5; ++i) acc[i] = b0;
  }
  const float* Ab = A + (size_t)rh * 80 * D_;
  for (int d0 = 0; d0 < D_; d0 += 64) {
    if (d0) __syncthreads();       // previous chunk's reads done
    // stage A[rh*80 : +80][d0:d0+64]: 1280 float4, 5 per thread, coalesced
#pragma unroll
    for (int k = 0; k < 5; ++k) {
      int idx = tid + k * 256;
      int row = idx >> 4, c4 = idx & 15;
      *(float4*)&sA[row][c4 * 4] =
          *(const float4*)&Ab[(size_t)row * D_ + d0 + c4 * 4];
    }
    __syncthreads();
#pragma unroll 2
    for (int dd = 0; dd < 64; dd += 4) {
      size_t wb = (size_t)(d0 + dd) * VOC_ + c;
      float4 w0 = *(const float4*)&Wout[wb];
      float4 w1 = *(const float4*)&Wout[wb + VOC_];
      float4 w2 = *(const float4*)&Wout[wb + 2 * (size_t)VOC_];
      float4 w3 = *(const float4*)&Wout[wb + 3 * (size_t)VOC_];
#pragma unroll
      for (int i = 0; i < 5; ++i) {
        float4 a = *(const float4*)&sA[rg * 5 + i][dd];
        acc[i].x = fmaf(a.x, w0.x, acc[i].x); acc[i].y = fmaf(a.x, w0.y, acc[i].y);
        acc[i].z = fmaf(a.x, w0.z, acc[i].z); acc[i].w = fmaf(a.x, w0.w, acc[i].w);
        acc[i].x = fmaf(a.y, w1.x, acc[i].x); acc[i].y = fmaf(a.y, w1.y, acc[i].y);
        acc[i].z = fmaf(a.y, w1.z, acc[i].z); acc[i].w = fmaf(a.y, w1.w, acc[i].w);
        acc[i].x = fmaf(a.z, w2.x, acc[i].x); acc[i].y = fmaf(a.z, w2.y, acc[i].y);
        acc[i].z = fmaf(a.z, w2.z, acc[i].z); acc[i].w = fmaf(a.z, w2.w, acc[i].w);
        acc[i].x = fmaf(a.w, w3.x, acc[i].x); acc[i].y = fmaf(a.w, w3.y, acc[i].y);
        acc[i].z = fmaf(a.w, w3.z, acc[i].z); acc[i].w = fmaf(a.w, w3.w, acc[i].w);
      }
    }
  }
#pragma unroll
  for (int i = 0; i < 5; ++i) {
    size_t o = (size_t)(rh * 80 + rg * 5 + i) * VOC_ + c;
    *(float4*)&wspred[o] = acc[i];
  }
}

// per-row softmax stats over VOC; w[b,p] = probs at x[b]
__global__ __launch_bounds__(256) void k_stats(const float* __restrict__ wspred,
    const int* __restrict__ x, float* __restrict__ ow) {
  __shared__ float red[256];
  int bp = blockIdx.x, tid = threadIdx.x;
  const float* row = wspred + (size_t)bp * VOC_;
  const float4* row4 = (const float4*)row;
  float m = -INFINITY;
  for (int i = tid; i < VOC_ / 4; i += 256) {
    float4 v = row4[i];
    m = fmaxf(m, fmaxf(fmaxf(v.x, v.y), fmaxf(v.z, v.w)));
  }
  red[tid] = m; __syncthreads();
  for (int s = 128; s > 0; s >>= 1) { if (tid < s) red[tid] = fmaxf(red[tid], red[tid + s]); __syncthreads(); }
  m = red[0]; __syncthreads();
  float sum = 0.f;
  for (int i = tid; i < VOC_ / 4; i += 256) {
    float4 v = row4[i];
    sum += expf(v.x - m) + expf(v.y - m) + expf(v.z - m) + expf(v.w - m);
  }
  red[tid] = sum; __syncthreads();
  for (int s = 128; s > 0; s >>= 1) { if (tid < s) red[tid] += red[tid + s]; __syncthreads(); }
  if (tid == 0) {
    int b = bp / P_;
    ow[bp] = expf(row[x[b]] - m) / red[0];
  }
}

// i_t via gumbel-argmax; argmax_w per batch
__global__ __launch_bounds__(256) void k_it(const float* __restrict__ ow,
    int* __restrict__ wsit, int* __restrict__ wsamw,
    uint32_t k5a, uint32_t k5b) {
  int tid = threadIdx.x;
  if (tid < NROW) {
    int b = tid / P_;
    float best = -INFINITY; int bi = 0;
#pragma unroll
    for (int i = 0; i < P_; ++i) {
      float g = jax_gumbel(k5a, k5b, (uint32_t)(tid * P_ + i));
      float v = g + ow[b * P_ + i];
      if (v > best) { best = v; bi = i; }
    }
    wsit[tid] = bi;
  }
  if (tid < B_) {
    float best = -INFINITY; int bi = 0;
#pragma unroll
    for (int p = 0; p < P_; ++p) {
      float v = ow[tid * P_ + p];
      if (v > best) { best = v; bi = p; }
    }
    wsamw[tid] = bi;
  }
}

// MERGED tail: blocks [0,2000) = avgmax; blocks [2000,2320) = zsel+I_new.
__global__ __launch_bounds__(256) void k_tail(const float* __restrict__ wspred,
    const float* __restrict__ ow, const int* __restrict__ wsamw,
    const float* __restrict__ wsz, const int* __restrict__ wsit,
    const int* __restrict__ I, const int* __restrict__ tptr,
    float* __restrict__ oavg, float* __restrict__ omax,
    float* __restrict__ oz, float* __restrict__ oI) {
  int bid = blockIdx.x, tid = threadIdx.x;
  if (bid < 2000) {
    int idx = bid * 256 + tid;
    if (idx >= B_ * VOC_) return;
    int b = idx / VOC_, c = idx % VOC_;
    float acc = 0.f;
#pragma unroll
    for (int p = 0; p < P_; ++p)
      acc = fmaf(wspred[(size_t)(b * P_ + p) * VOC_ + c], ow[b * P_ + p], acc);
    oavg[idx] = acc;
    omax[idx] = wspred[(size_t)(b * P_ + wsamw[b]) * VOC_ + c];
  } else {
    int idx = (bid - 2000) * 256 + tid;
    if (idx < NROW * D_) {
      int bp = idx / D_, d = idx % D_;
      int b = bp / P_;
      oz[idx] = wsz[(size_t)(b * P_ + wsit[bp]) * D_ + d];
    }
    if (idx < NROW * S_) {
      int bp = idx / S_, s = idx % S_;
      int ts = min(max(*tptr, 0), S_ - 1);
      oI[idx] = (s == ts) ? (float)wsit[bp] : (float)I[idx];
    }
  }
}

// ---------------- Host launch ----------------
static void derive_keys(uint32_t keys[5][2]) {
  for (int i = 0; i < 5; ++i) {
    U2 o = tf2x32(0u, 42u, 0u, (uint32_t)i);
    keys[i][0] = o.x; keys[i][1] = o.y;
  }
}

extern "C" void kernel_launch(void* const* d_in, const int* in_sizes, int n_in,
                              void* d_out, int out_size, void* d_ws, size_t ws_size,
                              hipStream_t stream) {
  const float* r   = (const float*)d_in[0];
  const int*   x   = (const int*)d_in[1];
  const float* K   = (const float*)d_in[2];
  const float* V   = (const float*)d_in[3];
  const int*   I   = (const int*)d_in[5];
  const int*   tp  = (const int*)d_in[6];
  const float* Wq  = (const float*)d_in[7];
  const float* bq  = (const float*)d_in[8];
  const float* Wk  = (const float*)d_in[9];
  const float* bk  = (const float*)d_in[10];
  const float* Wv  = (const float*)d_in[11];
  const float* bv  = (const float*)d_in[12];
  const float* Wo  = (const float*)d_in[13];
  const float* bo  = (const float*)d_in[14];
  const float* W1  = (const float*)d_in[15];
  const float* b1  = (const float*)d_in[16];
  const float* W2  = (const float*)d_in[17];
  const float* b2  = (const float*)d_in[18];
  const float* g1  = (const float*)d_in[19];
  const float* be1 = (const float*)d_in[20];
  const float* g3  = (const float*)d_in[21];
  const float* be3 = (const float*)d_in[22];
  const float* Wout = (const float*)d_in[23];
  const float* bout = (const float*)d_in[24];

  float* out = (float*)d_out;
  const size_t O_OUT3 = 0;
  const size_t O_Z    = 81920;
  const size_t O_AVG  = 163840;
  const size_t O_MAX  = 675840;
  const size_t O_EPS  = 1187840;
  const size_t O_AW   = 1269760;
  const size_t O_K    = 1290240;
  const size_t O_V    = 11776000;
  const size_t O_W    = 22261760;
  const size_t O_I    = 22261920;

  float* ws = (float*)d_ws;
  const size_t W_Q    = 0;
  const size_t W_CTX  = 81920;
  const size_t W_Z    = 163840;
  const size_t W_OUT1 = 245760;
  const size_t W_ATT  = 327680;   // 163840
  const size_t W_FFN  = 491520;   // 327680
  const size_t W_PRED = 819200;   // 5120000 -- also reused as K-split scratch
  const size_t W_IT   = 5939200;
  const size_t W_AMW  = 5939360;

  uint32_t kk[5][2];
  derive_keys(kk);

  float* oK = out + O_K;
  float* oV = out + O_V;
  float* sc = ws + W_PRED;        // K-split partial scratch (dead before k_preds)

  // launch 1: merged gather + qkv-partial (independent; overlap HBM vs L2)
  k_gq<<<1280 + 10240, 256, 0, stream>>>(K, V, I, oK, oV,
                                         r, Wq, bq, Wk, bk, Wv, bv,
                                         sc, sc + 655360, sc + 1310720);
  k_qkvr<<<320, 256, 0, stream>>>(sc, sc + 655360, sc + 1310720, tp,
                                  ws + W_Q, oK, oV,
                                  kk[0][0], kk[0][1], kk[1][0], kk[1][1],
                                  kk[2][0], kk[2][1]);
  k_attn<<<NROW * H_, 128, 0, stream>>>(ws + W_Q, oK, oV, ws + W_CTX, ws + W_ATT);
  // launch 4: merged zmat-partial + attn-weights (both depend only on k_attn)
  k_zaw<<<1280 + 80, 256, 0, stream>>>(ws + W_CTX, Wo, bo, sc,
                                       ws + W_ATT, out + O_AW);
  k_zmatr_ln<<<NROW, 256, 0, stream>>>(sc, r, g1, be1, out + O_EPS, ws + W_Z,
                                       ws + W_OUT1, kk[3][0], kk[3][1]);
  k_ffn1p<<<dim3(16, 20, 4), 128, 0, stream>>>(ws + W_OUT1, W1, b1, sc);
  k_ffn1r<<<1280, 256, 0, stream>>>(sc, ws + W_FFN);
  k_ffn2p<<<dim3(4, 40, 16), 128, 0, stream>>>(ws + W_FFN, W2, sc);
  k_ffn2r_ln<<<NROW, 256, 0, stream>>>(sc, b2, ws + W_OUT1, g3, be3, out + O_OUT3);
  k_preds<<<dim3(500, 2), 256, 0, stream>>>(out + O_OUT3, Wout, bout, ws + W_PRED);
  k_stats<<<NROW, 256, 0, stream>>>(ws + W_PRED, x, out + O_W);
  k_it<<<1, 256, 0, stream>>>(out + O_W, (int*)(ws + W_IT), (int*)(ws + W_AMW),
                              kk[4][0], kk[4][1]);
  k_tail<<<2320, 256, 0, stream>>>(ws + W_PRED, out + O_W,
                                   (const int*)(ws + W_AMW), ws + W_Z,
                                   (const int*)(ws + W_IT), I, tp,
                                   out + O_AVG, out + O_MAX,
                                   out + O_Z, out + O_I);
}